// Round 2
// baseline (273.177 us; speedup 1.0000x reference)
//
#include <hip/hip_runtime.h>

#define N_NODES 50000
#define D 128
#define N_EDGES 400000
#define NCHUNKS ((N_NODES + 255) / 256)   // 196
#define NBLK64 ((N_NODES + 63) / 64)      // 782
#define W_FRAG_SHORTS 16384               // 32 frags * 64 lanes * 8 bf16 per weight

#define MW_BLOCKS  64                     // 8 weights * 8 slot-blocks
#define HIST_BLOCKS ((N_EDGES + 255) / 256)   // 1563
#define PREP_BLOCKS (MW_BLOCKS + HIST_BLOCKS)

typedef short s8v  __attribute__((ext_vector_type(8)));   // 8 bf16 (4 VGPRs)
typedef float f4v  __attribute__((ext_vector_type(4)));   // MFMA accumulator

__device__ __forceinline__ unsigned int f2bf(float f) {
    unsigned int u = __float_as_uint(f);
    u += 0x7FFFu + ((u >> 16) & 1u);
    return u >> 16;
}
__device__ __forceinline__ unsigned int packbf(float a, float b) {
    return (f2bf(b) << 16) | f2bf(a);
}
__device__ __forceinline__ float bflo(unsigned int u) { return __uint_as_float(u << 16); }
__device__ __forceinline__ float bfhi(unsigned int u) { return __uint_as_float(u & 0xFFFF0000u); }
__device__ __forceinline__ float sigm(float x) {
    return __builtin_amdgcn_rcpf(1.f + __expf(-x));   // v_rcp_f32, ~1 ulp
}
// lane^1 neighbor swap via DPP quad_perm(1,0,3,2) — full-rate VALU, no LDS pipe
__device__ __forceinline__ float xor1(float x) {
    return __uint_as_float((unsigned int)__builtin_amdgcn_mov_dpp(
        (int)__float_as_uint(x), 0xB1, 0xF, 0xF, true));
}
// Split MFMA C-fragment column pairs across even/odd lanes:
// even lanes -> rows r0+0,r0+1 of colpair; odd lanes -> rows r0+2,r0+3.
__device__ __forceinline__ void pair_vals(const f4v a, int odd,
                                          float& loA, float& hiA,
                                          float& loB, float& hiB)
{
    const float e0 = xor1(a[0]), e1 = xor1(a[1]);
    const float e2 = xor1(a[2]), e3 = xor1(a[3]);
    loA = odd ? e2 : a[0];
    hiA = odd ? a[2] : e0;
    loB = odd ? e3 : a[1];
    hiB = odd ? a[3] : e1;
}
__device__ __forceinline__ void pack_pairs(const f4v a, int odd,
                                           unsigned int& wA, unsigned int& wB)
{
    float loA, hiA, loB, hiB;
    pair_vals(a, odd, loA, hiA, loB, hiB);
    wA = packbf(loA, hiA);
    wB = packbf(loB, hiB);
}

// ---------------------------------------------------------------------------
// Prep: [0,MW) weight frags | [MW, ...) tgt histogram.
// Wt layout per weight: frag = ntile*4 + kc, slot = frag*64 + lane, 8 bf16/lane
// == exact MFMA B-fragment per-lane layout (GEMM loads B direct from L2).
// ---------------------------------------------------------------------------
__global__ __launch_bounds__(256)
void prep_all(const float* __restrict__ W0, const float* __restrict__ W1,
              const float* __restrict__ W2, const float* __restrict__ W3,
              const float* __restrict__ W4, const float* __restrict__ W5,
              const float* __restrict__ W6, const float* __restrict__ W7,
              short* __restrict__ Wt,
              const int* __restrict__ tgt, int* __restrict__ counts)
{
    const int b = blockIdx.x;
    if (b < MW_BLOCKS) {
        const int wsel = b >> 3;
        const float* W = (wsel == 0) ? W0 : (wsel == 1) ? W1 : (wsel == 2) ? W2 :
                         (wsel == 3) ? W3 : (wsel == 4) ? W4 : (wsel == 5) ? W5 :
                         (wsel == 6) ? W6 : W7;
        const int slot = (b & 7) * 256 + threadIdx.x;
        const int frag = slot >> 6;
        const int lane = slot & 63;
        const int n    = (frag >> 2) * 16 + (lane & 15);
        const int kc   = frag & 3;
        const int quad = lane >> 4;
        const int k0   = kc * 32 + quad * 8;
        s8v v;
#pragma unroll
        for (int j = 0; j < 8; ++j)
            v[j] = (short)f2bf(W[(size_t)(k0 + j) * D + n]);
        *(s8v*)(Wt + (size_t)wsel * W_FRAG_SHORTS + (size_t)slot * 8) = v;
    } else {
        const int e = (b - MW_BLOCKS) * 256 + threadIdx.x;
        if (e < N_EDGES) atomicAdd(&counts[tgt[e]], 1);
    }
}

// ---------------------------------------------------------------------------
// Single-kernel CSR offset build (R8-verified).
// ---------------------------------------------------------------------------
__global__ __launch_bounds__(256)
void csr_scan(const int* __restrict__ counts, int* __restrict__ off,
              int* __restrict__ cursor, int* __restrict__ done_ctr,
              int* __restrict__ chunk_sum)
{
    __shared__ int s[256];
    const int b = blockIdx.x, t = threadIdx.x;
    const int i = b * 256 + t;
    const int v = (i < N_NODES) ? counts[i] : 0;
    s[t] = v;
    __syncthreads();
    for (int d = 1; d < 256; d <<= 1) {
        int tt = (t >= d) ? s[t - d] : 0;
        __syncthreads();
        s[t] += tt;
        __syncthreads();
    }
    const int incl = s[t];

    if (t == 255) {
        __hip_atomic_store(&chunk_sum[b], incl, __ATOMIC_RELAXED, __HIP_MEMORY_SCOPE_AGENT);
        __hip_atomic_fetch_add(done_ctr, 1, __ATOMIC_RELEASE, __HIP_MEMORY_SCOPE_AGENT);
    }
    if (t == 0) {
        while (__hip_atomic_load(done_ctr, __ATOMIC_ACQUIRE, __HIP_MEMORY_SCOPE_AGENT) < NCHUNKS)
            __builtin_amdgcn_s_sleep(8);
    }
    __syncthreads();

    const int pv = (t < b) ? __hip_atomic_load(&chunk_sum[t], __ATOMIC_RELAXED,
                                               __HIP_MEMORY_SCOPE_AGENT) : 0;
    __syncthreads();
    s[t] = pv;
    __syncthreads();
    for (int d = 128; d > 0; d >>= 1) {
        if (t < d) s[t] += s[t + d];
        __syncthreads();
    }
    const int base = s[0];

    if (i < N_NODES) {
        const int excl = base + incl - v;
        off[i]    = excl;
        cursor[i] = excl;
    }
    if (b == 0 && t == 0) off[N_NODES] = N_EDGES;
}

// ---------------------------------------------------------------------------
// 64-row GEMM phase: wave w owns cols [w*32, w*32+32), all 4 m-tiles.
// B frags straight from global Wt (L2-resident), A from LDS (swizzled).
// 32 MFMAs per phase per wave; no barriers anywhere in/after the phase.
// ---------------------------------------------------------------------------
__device__ __forceinline__
void mfma_phase64(const short* As, const short* __restrict__ Wf,
                  int lane, int w, f4v acc[4][2])
{
    s8v bv[2][4];
#pragma unroll
    for (int nt2 = 0; nt2 < 2; ++nt2)
#pragma unroll
        for (int kc = 0; kc < 4; ++kc)
            bv[nt2][kc] = *(const s8v*)(Wf + (((2 * w + nt2) * 4 + kc) * 64 + lane) * 8);
#pragma unroll
    for (int mt = 0; mt < 4; ++mt)
#pragma unroll
        for (int nt2 = 0; nt2 < 2; ++nt2)
            acc[mt][nt2] = (f4v){0.f, 0.f, 0.f, 0.f};
#pragma unroll
    for (int kc = 0; kc < 4; ++kc) {
        const int sl = (lane ^ (kc << 1)) * 8;
#pragma unroll
        for (int mt = 0; mt < 4; ++mt) {
            s8v a = *(const s8v*)&As[(mt * 4 + kc) * 512 + sl];
            acc[mt][0] = __builtin_amdgcn_mfma_f32_16x16x32_bf16(a, bv[0][kc], acc[mt][0], 0, 0, 0);
            acc[mt][1] = __builtin_amdgcn_mfma_f32_16x16x32_bf16(a, bv[1][kc], acc[mt][1], 0, 0, 0);
        }
    }
}

// ---------------------------------------------------------------------------
// Fused 4-projection GEMM tile, 64 rows, ONE barrier per block.
// Phases K | Q,V (joint reg-held epilogue) | S. Epilogues pack bf16 pairs
// in-register via DPP lane^1 swap and store direct to global — no C-LDS
// roundtrip, no store-drain barriers.
// ---------------------------------------------------------------------------
template<bool X_FP32, bool AGG_BF16>
__device__ __forceinline__
void gemm_tile(int m0, const float* __restrict__ Xf, const short* __restrict__ Xb,
               const short* __restrict__ WtL, const float* __restrict__ bias,
               unsigned int* __restrict__ Kw, unsigned int* __restrict__ QV,
               float* __restrict__ AggF, unsigned int* __restrict__ AggB,
               short* As, float* biasS)
{
    const int tid  = threadIdx.x;
    const int lane = tid & 63;
    const int w    = tid >> 6;

    if (tid < 128) biasS[tid] = bias[tid];

    // ---- Stage A (64 rows x 128 k, bf16) fragment-major, swizzled ----
#pragma unroll
    for (int i = 0; i < 4; ++i) {
        const int m   = (tid >> 4) + 16 * i;
        const int oct = tid & 15;
        const int row = m0 + m;
        s8v v = (s8v){0, 0, 0, 0, 0, 0, 0, 0};
        if (row < N_NODES) {
            if (X_FP32) {
                const float* p = Xf + (size_t)row * D + oct * 8;
                float4 a0 = *(const float4*)p;
                float4 a1 = *(const float4*)(p + 4);
                v[0] = (short)f2bf(a0.x); v[1] = (short)f2bf(a0.y);
                v[2] = (short)f2bf(a0.z); v[3] = (short)f2bf(a0.w);
                v[4] = (short)f2bf(a1.x); v[5] = (short)f2bf(a1.y);
                v[6] = (short)f2bf(a1.z); v[7] = (short)f2bf(a1.w);
            } else {
                v = *(const s8v*)(Xb + (size_t)row * D + oct * 8);
            }
        }
        const int kc = oct >> 2, quad = oct & 3;
        const int frag = (m >> 4) * 4 + kc;
        const int slot = ((m & 15) + 16 * quad) ^ (kc << 1);
        *(s8v*)&As[frag * 512 + slot * 8] = v;
    }
    __syncthreads();      // the ONLY block-wide barrier

    const int odd  = lane & 1;
    const int qrow = (lane >> 4) * 4;        // row base within 16-row tile
    const int cp   = (lane & 15) >> 1;       // colpair within 16-col tile

    f4v acc[4][2], accV[4][2];

    // ================= Phase K (sel 0) =================
    mfma_phase64(As, WtL + 0 * W_FRAG_SHORTS, lane, w, acc);
#pragma unroll
    for (int mt = 0; mt < 4; ++mt) {
        const int rA = m0 + mt * 16 + qrow + odd * 2;
#pragma unroll
        for (int nt2 = 0; nt2 < 2; ++nt2) {
            unsigned int wA, wB;
            pack_pairs(acc[mt][nt2], odd, wA, wB);
            const int wcol = w * 16 + nt2 * 8 + cp;
            if (rA < N_NODES)     Kw[(size_t)rA * 64 + wcol]       = wA;
            if (rA + 1 < N_NODES) Kw[(size_t)(rA + 1) * 64 + wcol] = wB;
        }
    }

    // ================= Phases Q + V (joint uint2 epilogue) =================
    mfma_phase64(As, WtL + 1 * W_FRAG_SHORTS, lane, w, acc);   // Q
    mfma_phase64(As, WtL + 2 * W_FRAG_SHORTS, lane, w, accV);  // V
#pragma unroll
    for (int mt = 0; mt < 4; ++mt) {
        const int rA = m0 + mt * 16 + qrow + odd * 2;
#pragma unroll
        for (int nt2 = 0; nt2 < 2; ++nt2) {
            unsigned int qA, qB, vA, vB;
            pack_pairs(acc[mt][nt2],  odd, qA, qB);
            pack_pairs(accV[mt][nt2], odd, vA, vB);
            const int wcol = w * 16 + nt2 * 8 + cp;
            if (rA < N_NODES)
                *(uint2*)&QV[(size_t)rA * 128 + wcol * 2]       = make_uint2(qA, vA);
            if (rA + 1 < N_NODES)
                *(uint2*)&QV[(size_t)(rA + 1) * 128 + wcol * 2] = make_uint2(qB, vB);
        }
    }

    // ================= Phase S (sel 3, skip + bias) =================
    mfma_phase64(As, WtL + 3 * W_FRAG_SHORTS, lane, w, acc);
    if (AGG_BF16) {
#pragma unroll
        for (int mt = 0; mt < 4; ++mt) {
            const int rA = m0 + mt * 16 + qrow + odd * 2;
#pragma unroll
            for (int nt2 = 0; nt2 < 2; ++nt2) {
                float loA, hiA, loB, hiB;
                pair_vals(acc[mt][nt2], odd, loA, hiA, loB, hiB);
                const int wcol = w * 16 + nt2 * 8 + cp;
                const float2 bp = *(const float2*)&biasS[2 * wcol];
                if (rA < N_NODES)
                    AggB[(size_t)rA * 64 + wcol]       = packbf(loA + bp.x, hiA + bp.y);
                if (rA + 1 < N_NODES)
                    AggB[(size_t)(rA + 1) * 64 + wcol] = packbf(loB + bp.x, hiB + bp.y);
            }
        }
    } else {
#pragma unroll
        for (int mt = 0; mt < 4; ++mt) {
            const int r0g = m0 + mt * 16 + qrow;
#pragma unroll
            for (int nt2 = 0; nt2 < 2; ++nt2) {
                const int col = w * 32 + nt2 * 16 + (lane & 15);
                const float b = biasS[col];
#pragma unroll
                for (int i = 0; i < 4; ++i) {
                    if (r0g + i < N_NODES)
                        AggF[(size_t)(r0g + i) * D + col] = acc[mt][nt2][i] + b;
                }
            }
        }
    }
}

// ---------------------------------------------------------------------------
// Layer-1 GEMM (fp32 x input, bf16 agg out) + fused edge scatter blocks.
// ---------------------------------------------------------------------------
__global__ __launch_bounds__(256, 3)
void gemm1_scatter(const float* __restrict__ X, const short* __restrict__ WtL,
                   const float* __restrict__ bias,
                   short* __restrict__ Kb, unsigned int* __restrict__ QV,
                   unsigned int* __restrict__ AggB,
                   const int* __restrict__ src, const int* __restrict__ tgt,
                   int* __restrict__ cursor, int* __restrict__ es)
{
    __shared__ __align__(16) short As[8192];    // 16 KB
    __shared__ __align__(16) float biasS[128];  // 0.5 KB

    if (blockIdx.x < NBLK64) {
        gemm_tile<true, true>(blockIdx.x * 64, X, nullptr, WtL, bias,
                              (unsigned int*)Kb, QV, nullptr, AggB, As, biasS);
    } else {
        const int e = (blockIdx.x - NBLK64) * 256 + threadIdx.x;
        if (e < N_EDGES) {
            int pos = atomicAdd(&cursor[tgt[e]], 1);
            es[pos] = src[e];
        }
    }
}

// Layer-2 GEMM (bf16 relu(h) input, fp32 agg -> d_out).
__global__ __launch_bounds__(256, 3)
void gemm2(const short* __restrict__ Hb, const short* __restrict__ WtL,
           const float* __restrict__ bias,
           short* __restrict__ Kb, unsigned int* __restrict__ QV,
           float* __restrict__ AggF)
{
    __shared__ __align__(16) short As[8192];
    __shared__ __align__(16) float biasS[128];
    gemm_tile<false, false>(blockIdx.x * 64, nullptr, Hb, WtL, bias,
                            (unsigned int*)Kb, QV, AggF, nullptr, As, biasS);
}

// ---------------------------------------------------------------------------
// Atomic-free per-node aggregation. One wave per node. 8-wide gather stage:
// one lane-parallel es load + readlane (8 uint2 gathers in flight).
// FIRST: Skip = bf16 agg1; out = bf16 relu -> Hb. Else: Skip = fp32 (d_out RMW).
// ---------------------------------------------------------------------------
template<bool FIRST>
__global__ __launch_bounds__(256)
void node_agg(const int* __restrict__ off, const int* __restrict__ es,
              const short* __restrict__ K, const unsigned int* __restrict__ QV,
              const void* __restrict__ Skip, float* __restrict__ OutF,
              unsigned int* __restrict__ Hb)
{
    const int lane = threadIdx.x & 63;
    const int t    = __builtin_amdgcn_readfirstlane(blockIdx.x * 4 + (threadIdx.x >> 6));

    const unsigned int ku = ((const unsigned int*)K)[(size_t)t * 64 + lane];
    const float kx = bflo(ku), ky = bfhi(ku);

    float skx, sky;
    if (FIRST) {
        const unsigned int su = ((const unsigned int*)Skip)[(size_t)t * 64 + lane];
        skx = bflo(su); sky = bfhi(su);
    } else {
        const float2 s2 = ((const float2*)Skip)[(size_t)t * 64 + lane];
        skx = s2.x; sky = s2.y;
    }

    float ax = 0.f, ay = 0.f, bx = 0.f, by = 0.f;
    const int e0 = __builtin_amdgcn_readfirstlane(off[t]);
    const int e1 = __builtin_amdgcn_readfirstlane(off[t + 1]);

    int e = e0;
    for (; e + 8 <= e1; e += 8) {
        const int sv = es[e + (lane & 7)];
        uint2 g[8];
#pragma unroll
        for (int u = 0; u < 8; ++u) {
            const int s = __builtin_amdgcn_readlane(sv, u);
            g[u] = ((const uint2*)(QV + (size_t)s * 128))[lane];
        }
#pragma unroll
        for (int u = 0; u < 8; ++u) {
            if (u & 1) {
                bx += bflo(g[u].y) * sigm(kx + bflo(g[u].x));
                by += bfhi(g[u].y) * sigm(ky + bfhi(g[u].x));
            } else {
                ax += bflo(g[u].y) * sigm(kx + bflo(g[u].x));
                ay += bfhi(g[u].y) * sigm(ky + bfhi(g[u].x));
            }
        }
    }
    if (e + 4 <= e1) {
        const int sv = es[e + (lane & 3)];
        uint2 g[4];
#pragma unroll
        for (int u = 0; u < 4; ++u) {
            const int s = __builtin_amdgcn_readlane(sv, u);
            g[u] = ((const uint2*)(QV + (size_t)s * 128))[lane];
        }
#pragma unroll
        for (int u = 0; u < 4; ++u) {
            if (u & 1) {
                bx += bflo(g[u].y) * sigm(kx + bflo(g[u].x));
                by += bfhi(g[u].y) * sigm(ky + bfhi(g[u].x));
            } else {
                ax += bflo(g[u].y) * sigm(kx + bflo(g[u].x));
                ay += bfhi(g[u].y) * sigm(ky + bfhi(g[u].x));
            }
        }
        e += 4;
    }
    for (; e < e1; ++e) {
        const int s0 = __builtin_amdgcn_readfirstlane(es[e]);
        const uint2 g0 = ((const uint2*)(QV + (size_t)s0 * 128))[lane];
        ax += bflo(g0.y) * sigm(kx + bflo(g0.x));
        ay += bfhi(g0.y) * sigm(ky + bfhi(g0.x));
    }

    const float rx = skx + ax + bx;
    const float ry = sky + ay + by;

    if (FIRST) {
        Hb[(size_t)t * 64 + lane] = packbf(fmaxf(rx, 0.f), fmaxf(ry, 0.f));
    } else {
        ((float2*)OutF)[(size_t)t * 64 + lane] = make_float2(rx, ry);
    }
}

extern "C" void kernel_launch(void* const* d_in, const int* in_sizes, int n_in,
                              void* d_out, int out_size, void* d_ws, size_t ws_size,
                              hipStream_t stream)
{
    const float* x   = (const float*)d_in[0];
    const int*   ei  = (const int*)d_in[1];
    const float* Wk1 = (const float*)d_in[2];
    const float* Wq1 = (const float*)d_in[3];
    const float* Wv1 = (const float*)d_in[4];
    const float* Ws1 = (const float*)d_in[5];
    const float* b1  = (const float*)d_in[6];
    const float* Wk2 = (const float*)d_in[7];
    const float* Wq2 = (const float*)d_in[8];
    const float* Wv2 = (const float*)d_in[9];
    const float* Ws2 = (const float*)d_in[10];
    const float* b2  = (const float*)d_in[11];

    const int* src = ei;
    const int* tgt = ei + N_EDGES;

    const size_t nd = (size_t)N_NODES * D;   // 6.4M elements
    short* kb   = (short*)d_ws;              // bf16 K                (nd shorts)
    short* qv   = kb + nd;                   // bf16 QV interleaved   (2*nd)
    short* hb   = qv + 2 * nd;               // bf16 relu(h)          (nd)
    short* ag1  = hb + nd;                   // bf16 x@Ws1+b1         (nd)
    short* wt   = ag1 + nd;                  // 8 * 16384 shorts
    int* counts    = (int*)(wt + 8 * W_FRAG_SHORTS);   // N_NODES
    int* done_ctr  = counts + N_NODES;                 // 1 (+1 pad)
    int* off       = counts + N_NODES + 2;             // N_NODES + 1
    int* cursor    = off + N_NODES + 1;                // N_NODES
    int* es        = cursor + N_NODES;                 // N_EDGES
    int* chunk_sum = es + N_EDGES;                     // NCHUNKS
    float* out = (float*)d_out;

    hipMemsetAsync(counts, 0, (N_NODES + 2) * sizeof(int), stream);
    prep_all<<<PREP_BLOCKS, 256, 0, stream>>>(Wk1, Wq1, Wv1, Ws1, Wk2, Wq2, Wv2, Ws2,
                                              wt, tgt, counts);
    csr_scan<<<NCHUNKS, 256, 0, stream>>>(counts, off, cursor, done_ctr, chunk_sum);

    // Layer 1 (+ fused edge scatter)
    gemm1_scatter<<<NBLK64 + HIST_BLOCKS, 256, 0, stream>>>(
        x, wt, b1, kb, (unsigned int*)qv, (unsigned int*)ag1, src, tgt, cursor, es);
    node_agg<true><<<N_NODES / 4, 256, 0, stream>>>(off, es, kb, (const unsigned int*)qv,
                                                    ag1, nullptr, (unsigned int*)hb);

    // Layer 2
    gemm2<<<NBLK64, 256, 0, stream>>>(hb, wt + 4 * W_FRAG_SHORTS, b2,
                                      kb, (unsigned int*)qv, out);
    node_agg<false><<<N_NODES / 4, 256, 0, stream>>>(off, es, kb, (const unsigned int*)qv,
                                                     out, out, nullptr);
}

// Round 3
// 269.854 us; speedup vs baseline: 1.0123x; 1.0123x over previous
//
#include <hip/hip_runtime.h>

#define N_NODES 50000
#define D 128
#define N_EDGES 400000
#define NCHUNKS ((N_NODES + 255) / 256)   // 196
#define NBLK32 ((N_NODES + 31) / 32)      // 1563
#define W_FRAG_SHORTS 16384               // 32 frags * 64 lanes * 8 bf16 per weight

#define MW_BLOCKS  64                     // 8 weights * 8 slot-blocks
#define HIST_BLOCKS ((N_EDGES + 255) / 256)   // 1563
#define PREP_BLOCKS (MW_BLOCKS + HIST_BLOCKS)

typedef short s8v  __attribute__((ext_vector_type(8)));   // 8 bf16 (4 VGPRs)
typedef float f4v  __attribute__((ext_vector_type(4)));   // MFMA accumulator

__device__ __forceinline__ unsigned int f2bf(float f) {
    unsigned int u = __float_as_uint(f);
    u += 0x7FFFu + ((u >> 16) & 1u);
    return u >> 16;
}
__device__ __forceinline__ unsigned int packbf(float a, float b) {
    return (f2bf(b) << 16) | f2bf(a);
}
__device__ __forceinline__ float bflo(unsigned int u) { return __uint_as_float(u << 16); }
__device__ __forceinline__ float bfhi(unsigned int u) { return __uint_as_float(u & 0xFFFF0000u); }
__device__ __forceinline__ float sigm(float x) {
    return __builtin_amdgcn_rcpf(1.f + __expf(-x));   // v_rcp_f32, ~1 ulp
}

// ---------------------------------------------------------------------------
// Prep: [0,MW) weight frags | [MW, ...) tgt histogram.
// Wt layout per weight: frag = ntile*4 + kc, slot = frag*64 + lane, 8 bf16/lane
// == exact MFMA B-fragment per-lane layout (GEMM loads B direct from L2).
// ---------------------------------------------------------------------------
__global__ __launch_bounds__(256)
void prep_all(const float* __restrict__ W0, const float* __restrict__ W1,
              const float* __restrict__ W2, const float* __restrict__ W3,
              const float* __restrict__ W4, const float* __restrict__ W5,
              const float* __restrict__ W6, const float* __restrict__ W7,
              short* __restrict__ Wt,
              const int* __restrict__ tgt, int* __restrict__ counts)
{
    const int b = blockIdx.x;
    if (b < MW_BLOCKS) {
        const int wsel = b >> 3;
        const float* W = (wsel == 0) ? W0 : (wsel == 1) ? W1 : (wsel == 2) ? W2 :
                         (wsel == 3) ? W3 : (wsel == 4) ? W4 : (wsel == 5) ? W5 :
                         (wsel == 6) ? W6 : W7;
        const int slot = (b & 7) * 256 + threadIdx.x;
        const int frag = slot >> 6;
        const int lane = slot & 63;
        const int n    = (frag >> 2) * 16 + (lane & 15);
        const int kc   = frag & 3;
        const int quad = lane >> 4;
        const int k0   = kc * 32 + quad * 8;
        s8v v;
#pragma unroll
        for (int j = 0; j < 8; ++j)
            v[j] = (short)f2bf(W[(size_t)(k0 + j) * D + n]);
        *(s8v*)(Wt + (size_t)wsel * W_FRAG_SHORTS + (size_t)slot * 8) = v;
    } else {
        const int e = (b - MW_BLOCKS) * 256 + threadIdx.x;
        if (e < N_EDGES) atomicAdd(&counts[tgt[e]], 1);
    }
}

// ---------------------------------------------------------------------------
// Single-kernel CSR offset build (R8-verified).
// ---------------------------------------------------------------------------
__global__ __launch_bounds__(256)
void csr_scan(const int* __restrict__ counts, int* __restrict__ off,
              int* __restrict__ cursor, int* __restrict__ done_ctr,
              int* __restrict__ chunk_sum)
{
    __shared__ int s[256];
    const int b = blockIdx.x, t = threadIdx.x;
    const int i = b * 256 + t;
    const int v = (i < N_NODES) ? counts[i] : 0;
    s[t] = v;
    __syncthreads();
    for (int d = 1; d < 256; d <<= 1) {
        int tt = (t >= d) ? s[t - d] : 0;
        __syncthreads();
        s[t] += tt;
        __syncthreads();
    }
    const int incl = s[t];

    if (t == 255) {
        __hip_atomic_store(&chunk_sum[b], incl, __ATOMIC_RELAXED, __HIP_MEMORY_SCOPE_AGENT);
        __hip_atomic_fetch_add(done_ctr, 1, __ATOMIC_RELEASE, __HIP_MEMORY_SCOPE_AGENT);
    }
    if (t == 0) {
        while (__hip_atomic_load(done_ctr, __ATOMIC_ACQUIRE, __HIP_MEMORY_SCOPE_AGENT) < NCHUNKS)
            __builtin_amdgcn_s_sleep(8);
    }
    __syncthreads();

    const int pv = (t < b) ? __hip_atomic_load(&chunk_sum[t], __ATOMIC_RELAXED,
                                               __HIP_MEMORY_SCOPE_AGENT) : 0;
    __syncthreads();
    s[t] = pv;
    __syncthreads();
    for (int d = 128; d > 0; d >>= 1) {
        if (t < d) s[t] += s[t + d];
        __syncthreads();
    }
    const int base = s[0];

    if (i < N_NODES) {
        const int excl = base + incl - v;
        off[i]    = excl;
        cursor[i] = excl;
    }
    if (b == 0 && t == 0) off[N_NODES] = N_EDGES;
}

// ---------------------------------------------------------------------------
// 32-row GEMM building blocks. Wave w owns cols [w*32, w*32+32).
// B frags direct from global Wt (L2-resident). A from LDS (swizzled, R1-verified).
// ---------------------------------------------------------------------------
__device__ __forceinline__
void load_b32(const short* __restrict__ Wf, int lane, int w, s8v bv[2][4])
{
#pragma unroll
    for (int nt2 = 0; nt2 < 2; ++nt2)
#pragma unroll
        for (int kc = 0; kc < 4; ++kc)
            bv[nt2][kc] = *(const s8v*)(Wf + (((2 * w + nt2) * 4 + kc) * 64 + lane) * 8);
}

__device__ __forceinline__
void mfma32(const short* As, const s8v bv[2][4], int lane, f4v acc[2][2])
{
#pragma unroll
    for (int mt = 0; mt < 2; ++mt)
#pragma unroll
        for (int nt2 = 0; nt2 < 2; ++nt2)
            acc[mt][nt2] = (f4v){0.f, 0.f, 0.f, 0.f};
#pragma unroll
    for (int kc = 0; kc < 4; ++kc) {
        const int sl = (lane ^ (kc << 1)) * 8;
        s8v a0 = *(const s8v*)&As[(0 * 4 + kc) * 512 + sl];
        s8v a1 = *(const s8v*)&As[(1 * 4 + kc) * 512 + sl];
#pragma unroll
        for (int nt2 = 0; nt2 < 2; ++nt2) {
            acc[0][nt2] = __builtin_amdgcn_mfma_f32_16x16x32_bf16(a0, bv[nt2][kc], acc[0][nt2], 0, 0, 0);
            acc[1][nt2] = __builtin_amdgcn_mfma_f32_16x16x32_bf16(a1, bv[nt2][kc], acc[1][nt2], 0, 0, 0);
        }
    }
}

// ---------------------------------------------------------------------------
// Wave-private fragment->row transpose via LDS. ZERO barriers (same-wave DS
// ops are in-order / lgkmcnt-tracked). Col-major storage in 16B units with
// XOR swizzle: logical (r,c) of the 32x32 slice lives at
//   u = c*8 + ((r>>2) ^ (c&7)), elem u*4 + (r&3).
// Write: ds_write_b128, uniform 8 lanes/bank-quad (optimal for b128).
// Read: ds_read_b32, 2 lanes/bank (free). out[j] = C[lane>>1][(lane&1)*16+j].
// ---------------------------------------------------------------------------
__device__ __forceinline__
void frag_rows(float* CsW, int lane, const f4v acc[2][2], float out[16])
{
    const int cl = lane & 15, rb = lane >> 4, x7 = lane & 7;
#pragma unroll
    for (int mt = 0; mt < 2; ++mt)
#pragma unroll
        for (int nt2 = 0; nt2 < 2; ++nt2) {
            const int lc = nt2 * 16 + cl;
            const int u  = lc * 8 + ((mt * 4 + rb) ^ x7);
            *(f4v*)&CsW[u * 4] = acc[mt][nt2];
        }
    const int lr = lane >> 1, ch = lane & 1;
#pragma unroll
    for (int j = 0; j < 16; ++j) {
        const int lc = ch * 16 + j;
        const int u  = lc * 8 + ((lr >> 2) ^ (lc & 7));
        out[j] = CsW[u * 4 + (lr & 3)];
    }
}

// ---------------------------------------------------------------------------
// Fused 4-projection GEMM tile, 32 rows, ONE barrier per block (after A-stage).
// Phases K | Q,V (joint uint4 epilogue) | S, all via wave-private transpose,
// fully coalesced 16-32B/lane stores.
// ---------------------------------------------------------------------------
template<bool X_FP32, bool AGG_BF16>
__device__ __forceinline__
void gemm_tile(int m0, const float* __restrict__ Xf, const short* __restrict__ Xb,
               const short* __restrict__ WtL, const float* __restrict__ bias,
               unsigned int* __restrict__ Kw, unsigned int* __restrict__ QV,
               float* __restrict__ AggF, unsigned int* __restrict__ AggB,
               short* As, float* Cs, float* biasS)
{
    const int tid  = threadIdx.x;
    const int lane = tid & 63;
    const int w    = tid >> 6;

    if (tid < 128) biasS[tid] = bias[tid];

    // ---- Stage A (32 rows x 128 k, bf16) fragment-major, swizzled ----
#pragma unroll
    for (int i = 0; i < 2; ++i) {
        const int m   = (tid >> 4) + 16 * i;
        const int oct = tid & 15;
        const int row = m0 + m;
        s8v v = (s8v){0, 0, 0, 0, 0, 0, 0, 0};
        if (row < N_NODES) {
            if (X_FP32) {
                const float* p = Xf + (size_t)row * D + oct * 8;
                float4 a0 = *(const float4*)p;
                float4 a1 = *(const float4*)(p + 4);
                v[0] = (short)f2bf(a0.x); v[1] = (short)f2bf(a0.y);
                v[2] = (short)f2bf(a0.z); v[3] = (short)f2bf(a0.w);
                v[4] = (short)f2bf(a1.x); v[5] = (short)f2bf(a1.y);
                v[6] = (short)f2bf(a1.z); v[7] = (short)f2bf(a1.w);
            } else {
                v = *(const s8v*)(Xb + (size_t)row * D + oct * 8);
            }
        }
        const int kc = oct >> 2, quad = oct & 3;
        const int frag = (m >> 4) * 4 + kc;
        const int slot = ((m & 15) + 16 * quad) ^ (kc << 1);
        *(s8v*)&As[frag * 512 + slot * 8] = v;
    }
    __syncthreads();      // the ONLY block-wide barrier

    float* CsW = Cs + w * 1024;          // 4 KB fp32 slice per wave
    const int lr   = lane >> 1;          // row 0..31 this lane packs/stores
    const int ch   = lane & 1;           // col-half (16 cols)
    const int grow = m0 + lr;
    const bool rok = grow < N_NODES;

    f4v acc[2][2];
    s8v bv[2][4];
    float ro[16];

    // ================= Phase K (sel 0) =================
    load_b32(WtL + 0 * W_FRAG_SHORTS, lane, w, bv);
    mfma32(As, bv, lane, acc);
    frag_rows(CsW, lane, acc, ro);
    if (rok) {
        unsigned int kp[8];
#pragma unroll
        for (int i = 0; i < 8; ++i) kp[i] = packbf(ro[2 * i], ro[2 * i + 1]);
        unsigned int* kb = Kw + (size_t)grow * 64 + w * 16 + ch * 8;
        *(uint4*)kb       = make_uint4(kp[0], kp[1], kp[2], kp[3]);
        *(uint4*)(kb + 4) = make_uint4(kp[4], kp[5], kp[6], kp[7]);
    }

    // ================= Phases Q + V (joint interleaved epilogue) ===========
    load_b32(WtL + 1 * W_FRAG_SHORTS, lane, w, bv);
    mfma32(As, bv, lane, acc);           // Q
    frag_rows(CsW, lane, acc, ro);
    unsigned int qp[8];
#pragma unroll
    for (int i = 0; i < 8; ++i) qp[i] = packbf(ro[2 * i], ro[2 * i + 1]);

    load_b32(WtL + 2 * W_FRAG_SHORTS, lane, w, bv);
    mfma32(As, bv, lane, acc);           // V
    frag_rows(CsW, lane, acc, ro);
    if (rok) {
        unsigned int* qb = QV + (size_t)grow * 128 + (w * 16 + ch * 8) * 2;
#pragma unroll
        for (int i = 0; i < 8; i += 2) {
            *(uint4*)(qb + 2 * i) = make_uint4(qp[i],     packbf(ro[2 * i],     ro[2 * i + 1]),
                                               qp[i + 1], packbf(ro[2 * i + 2], ro[2 * i + 3]));
        }
    }

    // ================= Phase S (sel 3, skip + bias) =================
    load_b32(WtL + 3 * W_FRAG_SHORTS, lane, w, bv);
    mfma32(As, bv, lane, acc);
    frag_rows(CsW, lane, acc, ro);
#pragma unroll
    for (int j = 0; j < 16; ++j) ro[j] += biasS[w * 32 + ch * 16 + j];
    if (rok) {
        if (AGG_BF16) {
            unsigned int ap[8];
#pragma unroll
            for (int i = 0; i < 8; ++i) ap[i] = packbf(ro[2 * i], ro[2 * i + 1]);
            unsigned int* ab = AggB + (size_t)grow * 64 + w * 16 + ch * 8;
            *(uint4*)ab       = make_uint4(ap[0], ap[1], ap[2], ap[3]);
            *(uint4*)(ab + 4) = make_uint4(ap[4], ap[5], ap[6], ap[7]);
        } else {
            float* ob = AggF + (size_t)grow * D + w * 32 + ch * 16;
#pragma unroll
            for (int q = 0; q < 4; ++q)
                *(float4*)(ob + 4 * q) = make_float4(ro[4 * q], ro[4 * q + 1],
                                                     ro[4 * q + 2], ro[4 * q + 3]);
        }
    }
}

// ---------------------------------------------------------------------------
// Layer-1 GEMM + fused edge scatter. Scatter blocks FIRST in the grid: they
// are short (256 atomics + stores) and drain quickly, letting the long GEMM
// cohort stream in behind them instead of the scatter serializing as a tail.
// ---------------------------------------------------------------------------
__global__ __launch_bounds__(256, 5)
void gemm1_scatter(const float* __restrict__ X, const short* __restrict__ WtL,
                   const float* __restrict__ bias,
                   unsigned int* __restrict__ Kw, unsigned int* __restrict__ QV,
                   unsigned int* __restrict__ AggB,
                   const int* __restrict__ src, const int* __restrict__ tgt,
                   int* __restrict__ cursor, int* __restrict__ es)
{
    __shared__ __align__(16) short As[4096];    // 8 KB
    __shared__ __align__(16) float Cs[4096];    // 16 KB (4 KB wave-private x4)
    __shared__ __align__(16) float biasS[128];  // 0.5 KB

    if (blockIdx.x >= HIST_BLOCKS) {
        gemm_tile<true, true>((blockIdx.x - HIST_BLOCKS) * 32, X, nullptr, WtL, bias,
                              Kw, QV, nullptr, AggB, As, Cs, biasS);
    } else {
        const int e = blockIdx.x * 256 + threadIdx.x;
        if (e < N_EDGES) {
            int pos = atomicAdd(&cursor[tgt[e]], 1);
            es[pos] = src[e];
        }
    }
}

// Layer-2 GEMM (bf16 relu(h) input, fp32 agg -> d_out).
__global__ __launch_bounds__(256, 5)
void gemm2(const short* __restrict__ Hb, const short* __restrict__ WtL,
           const float* __restrict__ bias,
           unsigned int* __restrict__ Kw, unsigned int* __restrict__ QV,
           float* __restrict__ AggF)
{
    __shared__ __align__(16) short As[4096];
    __shared__ __align__(16) float Cs[4096];
    __shared__ __align__(16) float biasS[128];
    gemm_tile<false, false>(blockIdx.x * 32, nullptr, Hb, WtL, bias,
                            Kw, QV, AggF, nullptr, As, Cs, biasS);
}

// ---------------------------------------------------------------------------
// Atomic-free per-node aggregation. One wave per node. 8-wide gather stage:
// one lane-parallel es load + readlane (8 uint2 gathers in flight).
// FIRST: Skip = bf16 agg1; out = bf16 relu -> Hb. Else: Skip = fp32 (d_out RMW).
// ---------------------------------------------------------------------------
template<bool FIRST>
__global__ __launch_bounds__(256)
void node_agg(const int* __restrict__ off, const int* __restrict__ es,
              const short* __restrict__ K, const unsigned int* __restrict__ QV,
              const void* __restrict__ Skip, float* __restrict__ OutF,
              unsigned int* __restrict__ Hb)
{
    const int lane = threadIdx.x & 63;
    const int t    = __builtin_amdgcn_readfirstlane(blockIdx.x * 4 + (threadIdx.x >> 6));

    const unsigned int ku = ((const unsigned int*)K)[(size_t)t * 64 + lane];
    const float kx = bflo(ku), ky = bfhi(ku);

    float skx, sky;
    if (FIRST) {
        const unsigned int su = ((const unsigned int*)Skip)[(size_t)t * 64 + lane];
        skx = bflo(su); sky = bfhi(su);
    } else {
        const float2 s2 = ((const float2*)Skip)[(size_t)t * 64 + lane];
        skx = s2.x; sky = s2.y;
    }

    float ax = 0.f, ay = 0.f, bx = 0.f, by = 0.f;
    const int e0 = __builtin_amdgcn_readfirstlane(off[t]);
    const int e1 = __builtin_amdgcn_readfirstlane(off[t + 1]);

    int e = e0;
    for (; e + 8 <= e1; e += 8) {
        const int sv = es[e + (lane & 7)];
        uint2 g[8];
#pragma unroll
        for (int u = 0; u < 8; ++u) {
            const int s = __builtin_amdgcn_readlane(sv, u);
            g[u] = ((const uint2*)(QV + (size_t)s * 128))[lane];
        }
#pragma unroll
        for (int u = 0; u < 8; ++u) {
            if (u & 1) {
                bx += bflo(g[u].y) * sigm(kx + bflo(g[u].x));
                by += bfhi(g[u].y) * sigm(ky + bfhi(g[u].x));
            } else {
                ax += bflo(g[u].y) * sigm(kx + bflo(g[u].x));
                ay += bfhi(g[u].y) * sigm(ky + bfhi(g[u].x));
            }
        }
    }
    if (e + 4 <= e1) {
        const int sv = es[e + (lane & 3)];
        uint2 g[4];
#pragma unroll
        for (int u = 0; u < 4; ++u) {
            const int s = __builtin_amdgcn_readlane(sv, u);
            g[u] = ((const uint2*)(QV + (size_t)s * 128))[lane];
        }
#pragma unroll
        for (int u = 0; u < 4; ++u) {
            if (u & 1) {
                bx += bflo(g[u].y) * sigm(kx + bflo(g[u].x));
                by += bfhi(g[u].y) * sigm(ky + bfhi(g[u].x));
            } else {
                ax += bflo(g[u].y) * sigm(kx + bflo(g[u].x));
                ay += bfhi(g[u].y) * sigm(ky + bfhi(g[u].x));
            }
        }
        e += 4;
    }
    for (; e < e1; ++e) {
        const int s0 = __builtin_amdgcn_readfirstlane(es[e]);
        const uint2 g0 = ((const uint2*)(QV + (size_t)s0 * 128))[lane];
        ax += bflo(g0.y) * sigm(kx + bflo(g0.x));
        ay += bfhi(g0.y) * sigm(ky + bfhi(g0.x));
    }

    const float rx = skx + ax + bx;
    const float ry = sky + ay + by;

    if (FIRST) {
        Hb[(size_t)t * 64 + lane] = packbf(fmaxf(rx, 0.f), fmaxf(ry, 0.f));
    } else {
        ((float2*)OutF)[(size_t)t * 64 + lane] = make_float2(rx, ry);
    }
}

extern "C" void kernel_launch(void* const* d_in, const int* in_sizes, int n_in,
                              void* d_out, int out_size, void* d_ws, size_t ws_size,
                              hipStream_t stream)
{
    const float* x   = (const float*)d_in[0];
    const int*   ei  = (const int*)d_in[1];
    const float* Wk1 = (const float*)d_in[2];
    const float* Wq1 = (const float*)d_in[3];
    const float* Wv1 = (const float*)d_in[4];
    const float* Ws1 = (const float*)d_in[5];
    const float* b1  = (const float*)d_in[6];
    const float* Wk2 = (const float*)d_in[7];
    const float* Wq2 = (const float*)d_in[8];
    const float* Wv2 = (const float*)d_in[9];
    const float* Ws2 = (const float*)d_in[10];
    const float* b2  = (const float*)d_in[11];

    const int* src = ei;
    const int* tgt = ei + N_EDGES;

    const size_t nd = (size_t)N_NODES * D;   // 6.4M elements
    short* kb   = (short*)d_ws;              // bf16 K                (nd shorts)
    short* qv   = kb + nd;                   // bf16 QV interleaved   (2*nd)
    short* hb   = qv + 2 * nd;               // bf16 relu(h)          (nd)
    short* ag1  = hb + nd;                   // bf16 x@Ws1+b1         (nd)
    short* wt   = ag1 + nd;                  // 8 * 16384 shorts
    int* counts    = (int*)(wt + 8 * W_FRAG_SHORTS);   // N_NODES
    int* done_ctr  = counts + N_NODES;                 // 1 (+1 pad)
    int* off       = counts + N_NODES + 2;             // N_NODES + 1
    int* cursor    = off + N_NODES + 1;                // N_NODES
    int* es        = cursor + N_NODES;                 // N_EDGES
    int* chunk_sum = es + N_EDGES;                     // NCHUNKS
    float* out = (float*)d_out;

    hipMemsetAsync(counts, 0, (N_NODES + 2) * sizeof(int), stream);
    prep_all<<<PREP_BLOCKS, 256, 0, stream>>>(Wk1, Wq1, Wv1, Ws1, Wk2, Wq2, Wv2, Ws2,
                                              wt, tgt, counts);
    csr_scan<<<NCHUNKS, 256, 0, stream>>>(counts, off, cursor, done_ctr, chunk_sum);

    // Layer 1 (+ fused edge scatter, scatter blocks first)
    gemm1_scatter<<<NBLK32 + HIST_BLOCKS, 256, 0, stream>>>(
        x, wt, b1, (unsigned int*)kb, (unsigned int*)qv, (unsigned int*)ag1,
        src, tgt, cursor, es);
    node_agg<true><<<N_NODES / 4, 256, 0, stream>>>(off, es, kb, (const unsigned int*)qv,
                                                    ag1, nullptr, (unsigned int*)hb);

    // Layer 2
    gemm2<<<NBLK32, 256, 0, stream>>>(hb, wt + 4 * W_FRAG_SHORTS, b2,
                                      (unsigned int*)kb, (unsigned int*)qv, out);
    node_agg<false><<<N_NODES / 4, 256, 0, stream>>>(off, es, kb, (const unsigned int*)qv,
                                                     out, out, nullptr);
}

// Round 5
// 262.190 us; speedup vs baseline: 1.0419x; 1.0292x over previous
//
#include <hip/hip_runtime.h>

#define N_NODES 50000
#define D 128
#define N_EDGES 400000
#define NCHUNKS ((N_NODES + 255) / 256)   // 196
#define NBLK64 ((N_NODES + 63) / 64)      // 782
#define NBLK32 ((N_NODES + 31) / 31 == 0 ? 0 : (N_NODES + 31) / 32)  // 1563
#define W_FRAG_SHORTS 16384               // 32 frags * 64 lanes * 8 bf16 per weight

#define MW_BLOCKS  64                     // 8 weights * 8 slot-blocks
#define HIST_BLOCKS ((N_EDGES + 255) / 256)   // 1563
#define PREP_BLOCKS (MW_BLOCKS + HIST_BLOCKS)

typedef short s8v  __attribute__((ext_vector_type(8)));   // 8 bf16 (4 VGPRs)
typedef float f4v  __attribute__((ext_vector_type(4)));   // MFMA accumulator

__device__ __forceinline__ unsigned int f2bf(float f) {
    unsigned int u = __float_as_uint(f);
    u += 0x7FFFu + ((u >> 16) & 1u);
    return u >> 16;
}
__device__ __forceinline__ unsigned int packbf(float a, float b) {
    return (f2bf(b) << 16) | f2bf(a);
}
__device__ __forceinline__ float bflo(unsigned int u) { return __uint_as_float(u << 16); }
__device__ __forceinline__ float bfhi(unsigned int u) { return __uint_as_float(u & 0xFFFF0000u); }
__device__ __forceinline__ float sigm(float x) {
    return __builtin_amdgcn_rcpf(1.f + __expf(-x));   // v_rcp_f32, ~1 ulp
}

// ---------------------------------------------------------------------------
// Prep: [0,MW) weight frags | [MW, ...) tgt histogram.
// ---------------------------------------------------------------------------
__global__ __launch_bounds__(256)
void prep_all(const float* __restrict__ W0, const float* __restrict__ W1,
              const float* __restrict__ W2, const float* __restrict__ W3,
              const float* __restrict__ W4, const float* __restrict__ W5,
              const float* __restrict__ W6, const float* __restrict__ W7,
              short* __restrict__ Wt,
              const int* __restrict__ tgt, int* __restrict__ counts)
{
    const int b = blockIdx.x;
    if (b < MW_BLOCKS) {
        const int wsel = b >> 3;
        const float* W = (wsel == 0) ? W0 : (wsel == 1) ? W1 : (wsel == 2) ? W2 :
                         (wsel == 3) ? W3 : (wsel == 4) ? W4 : (wsel == 5) ? W5 :
                         (wsel == 6) ? W6 : W7;
        const int slot = (b & 7) * 256 + threadIdx.x;
        const int frag = slot >> 6;
        const int lane = slot & 63;
        const int n    = (frag >> 2) * 16 + (lane & 15);
        const int kc   = frag & 3;
        const int quad = lane >> 4;
        const int k0   = kc * 32 + quad * 8;
        s8v v;
#pragma unroll
        for (int j = 0; j < 8; ++j)
            v[j] = (short)f2bf(W[(size_t)(k0 + j) * D + n]);
        *(s8v*)(Wt + (size_t)wsel * W_FRAG_SHORTS + (size_t)slot * 8) = v;
    } else {
        const int e = (b - MW_BLOCKS) * 256 + threadIdx.x;
        if (e < N_EDGES) atomicAdd(&counts[tgt[e]], 1);
    }
}

// ---------------------------------------------------------------------------
// Single-kernel CSR offset build (R8-verified).
// ---------------------------------------------------------------------------
__global__ __launch_bounds__(256)
void csr_scan(const int* __restrict__ counts, int* __restrict__ off,
              int* __restrict__ cursor, int* __restrict__ done_ctr,
              int* __restrict__ chunk_sum)
{
    __shared__ int s[256];
    const int b = blockIdx.x, t = threadIdx.x;
    const int i = b * 256 + t;
    const int v = (i < N_NODES) ? counts[i] : 0;
    s[t] = v;
    __syncthreads();
    for (int d = 1; d < 256; d <<= 1) {
        int tt = (t >= d) ? s[t - d] : 0;
        __syncthreads();
        s[t] += tt;
        __syncthreads();
    }
    const int incl = s[t];

    if (t == 255) {
        __hip_atomic_store(&chunk_sum[b], incl, __ATOMIC_RELAXED, __HIP_MEMORY_SCOPE_AGENT);
        __hip_atomic_fetch_add(done_ctr, 1, __ATOMIC_RELEASE, __HIP_MEMORY_SCOPE_AGENT);
    }
    if (t == 0) {
        while (__hip_atomic_load(done_ctr, __ATOMIC_ACQUIRE, __HIP_MEMORY_SCOPE_AGENT) < NCHUNKS)
            __builtin_amdgcn_s_sleep(8);
    }
    __syncthreads();

    const int pv = (t < b) ? __hip_atomic_load(&chunk_sum[t], __ATOMIC_RELAXED,
                                               __HIP_MEMORY_SCOPE_AGENT) : 0;
    __syncthreads();
    s[t] = pv;
    __syncthreads();
    for (int d = 128; d > 0; d >>= 1) {
        if (t < d) s[t] += s[t + d];
        __syncthreads();
    }
    const int base = s[0];

    if (i < N_NODES) {
        const int excl = base + incl - v;
        off[i]    = excl;
        cursor[i] = excl;
    }
    if (b == 0 && t == 0) off[N_NODES] = N_EDGES;
}

// ===========================================================================
// gemm1: R0 structure (64-row tile, LDS-staged B via global_load_lds,
// block-wide C roundtrip). Empirically fastest gemm1 (43.5 us steady).
// ===========================================================================
__device__ __forceinline__
void stage_b(const short* __restrict__ Wf, short* Bs, int tid)
{
#pragma unroll
    for (int j = 0; j < 8; ++j) {
        const int chunk = tid + 256 * j;
        __builtin_amdgcn_global_load_lds(
            (const __attribute__((address_space(1))) unsigned int*)(Wf + chunk * 8),
            (__attribute__((address_space(3))) unsigned int*)(&Bs[(chunk & ~63) * 8]),
            16, 0, 0);
    }
}

__device__ __forceinline__
void mfma_phase(const short* As, const short* Bs, int lane, int wr, int wc,
                f4v acc[2][4])
{
#pragma unroll
    for (int mt = 0; mt < 2; ++mt)
#pragma unroll
        for (int nt = 0; nt < 4; ++nt)
            acc[mt][nt] = (f4v){0.f, 0.f, 0.f, 0.f};
#pragma unroll
    for (int kc = 0; kc < 4; ++kc) {
        const int sl = (lane ^ (kc << 1)) * 8;
        s8v a0 = *(const s8v*)&As[((2 * wr + 0) * 4 + kc) * 512 + sl];
        s8v a1 = *(const s8v*)&As[((2 * wr + 1) * 4 + kc) * 512 + sl];
#pragma unroll
        for (int nt = 0; nt < 4; ++nt) {
            s8v b = *(const s8v*)&Bs[((4 * wc + nt) * 4 + kc) * 512 + lane * 8];
            acc[0][nt] = __builtin_amdgcn_mfma_f32_16x16x32_bf16(a0, b, acc[0][nt], 0, 0, 0);
            acc[1][nt] = __builtin_amdgcn_mfma_f32_16x16x32_bf16(a1, b, acc[1][nt], 0, 0, 0);
        }
    }
}

__device__ __forceinline__
void c_to_lds(float* Cs, int lane, int wr, int wc, const f4v acc[2][4])
{
#pragma unroll
    for (int mt = 0; mt < 2; ++mt) {
        const int r0 = wr * 32 + mt * 16 + (lane >> 4) * 4;
#pragma unroll
        for (int nt = 0; nt < 4; ++nt) {
            const int col = wc * 64 + nt * 16 + (lane & 15);
            const int g = col >> 2, jj = col & 3;
#pragma unroll
            for (int i = 0; i < 4; ++i) {
                const int row = r0 + i;
                const int gs  = g ^ (((row >> 2) & 3) << 2);
                Cs[row * 128 + gs * 4 + jj] = acc[mt][nt][i];
            }
        }
    }
}

__device__ __forceinline__
void gemm_tile64(int m0, const float* __restrict__ Xf,
                 const short* __restrict__ WtL, const float* __restrict__ bias,
                 short* __restrict__ Kb, unsigned int* __restrict__ QV,
                 unsigned int* __restrict__ AggB,
                 short* As, short* Bs, float* biasS)
{
    const int tid  = threadIdx.x;
    const int lane = tid & 63;
    const int w    = tid >> 6;
    const int wr   = w & 1;
    const int wc   = w >> 1;

    if (tid < 128) biasS[tid] = bias[tid];

    // ---- Stage A (64 rows x 128 k, fp32->bf16) fragment-major, swizzled ----
#pragma unroll
    for (int i = 0; i < 4; ++i) {
        const int m   = (tid >> 4) + 16 * i;
        const int oct = tid & 15;
        const int row = m0 + m;
        s8v v = (s8v){0, 0, 0, 0, 0, 0, 0, 0};
        if (row < N_NODES) {
            const float* p = Xf + (size_t)row * D + oct * 8;
            float4 a0 = *(const float4*)p;
            float4 a1 = *(const float4*)(p + 4);
            v[0] = (short)f2bf(a0.x); v[1] = (short)f2bf(a0.y);
            v[2] = (short)f2bf(a0.z); v[3] = (short)f2bf(a0.w);
            v[4] = (short)f2bf(a1.x); v[5] = (short)f2bf(a1.y);
            v[6] = (short)f2bf(a1.z); v[7] = (short)f2bf(a1.w);
        }
        const int kc = oct >> 2, quad = oct & 3;
        const int frag = (m >> 4) * 4 + kc;
        const int slot = ((m & 15) + 16 * quad) ^ (kc << 1);
        *(s8v*)&As[frag * 512 + slot * 8] = v;
    }

    float* Cs = (float*)Bs;
    f4v acc[2][4];

    // ================= Phase K (sel 0) =================
    __syncthreads();
    stage_b(WtL + 0 * W_FRAG_SHORTS, Bs, tid);
    __syncthreads();
    mfma_phase(As, Bs, lane, wr, wc, acc);
    __syncthreads();
    c_to_lds(Cs, lane, wr, wc, acc);
    __syncthreads();
#pragma unroll
    for (int j = 0; j < 8; ++j) {
        const int c   = tid + 256 * j;
        const int row = c >> 5, gg = c & 31;
        const int gs  = gg ^ (((row >> 2) & 3) << 2);
        const f4v vv  = *(const f4v*)&Cs[row * 128 + gs * 4];
        const int grow = m0 + row;
        if (grow < N_NODES) {
            uint2* kp = (uint2*)((unsigned int*)Kb + (size_t)grow * 64 + gg * 2);
            *kp = make_uint2(packbf(vv[0], vv[1]), packbf(vv[2], vv[3]));
        }
    }

    // ================= Phase QV (sel 1 + 2, joint epilogue) =================
    f4v accV[2][4];
    __syncthreads();                       // Cs readers done
    stage_b(WtL + 1 * W_FRAG_SHORTS, Bs, tid);
    __syncthreads();
    mfma_phase(As, Bs, lane, wr, wc, acc);  // Q
    __syncthreads();
    stage_b(WtL + 2 * W_FRAG_SHORTS, Bs, tid);
    __syncthreads();
    mfma_phase(As, Bs, lane, wr, wc, accV); // V
    __syncthreads();
    c_to_lds(Cs, lane, wr, wc, acc);        // Q roundtrip
    __syncthreads();
    unsigned int qp0[8], qp1[8];
#pragma unroll
    for (int j = 0; j < 8; ++j) {
        const int c   = tid + 256 * j;
        const int row = c >> 5, gg = c & 31;
        const int gs  = gg ^ (((row >> 2) & 3) << 2);
        const f4v vv  = *(const f4v*)&Cs[row * 128 + gs * 4];
        qp0[j] = packbf(vv[0], vv[1]);
        qp1[j] = packbf(vv[2], vv[3]);
    }
    __syncthreads();
    c_to_lds(Cs, lane, wr, wc, accV);       // V roundtrip
    __syncthreads();
#pragma unroll
    for (int j = 0; j < 8; ++j) {
        const int c   = tid + 256 * j;
        const int row = c >> 5, gg = c & 31;
        const int gs  = gg ^ (((row >> 2) & 3) << 2);
        const f4v vv  = *(const f4v*)&Cs[row * 128 + gs * 4];
        const int grow = m0 + row;
        if (grow < N_NODES) {
            uint4* qvp = (uint4*)(QV + (size_t)grow * 128 + gg * 4);
            *qvp = make_uint4(qp0[j], packbf(vv[0], vv[1]),
                              qp1[j], packbf(vv[2], vv[3]));
        }
    }

    // ================= Phase S (sel 3, skip + bias, bf16 out) ==============
    __syncthreads();
    stage_b(WtL + 3 * W_FRAG_SHORTS, Bs, tid);
    __syncthreads();
    mfma_phase(As, Bs, lane, wr, wc, acc);
    __syncthreads();
    c_to_lds(Cs, lane, wr, wc, acc);
    __syncthreads();
#pragma unroll
    for (int j = 0; j < 8; ++j) {
        const int c   = tid + 256 * j;
        const int row = c >> 5, gg = c & 31;
        const int gs  = gg ^ (((row >> 2) & 3) << 2);
        const f4v vv  = *(const f4v*)&Cs[row * 128 + gs * 4];
        const int grow = m0 + row;
        if (grow >= N_NODES) continue;
        const float4 bv = *(const float4*)&biasS[gg * 4];
        uint2* ap = (uint2*)(AggB + (size_t)grow * 64 + gg * 2);
        *ap = make_uint2(packbf(vv[0] + bv.x, vv[1] + bv.y),
                         packbf(vv[2] + bv.z, vv[3] + bv.w));
    }
}

// ===========================================================================
// gemm2: R1 structure (32-row tile, B direct from L2, block C roundtrip).
// Empirically the faster gemm2 (~8 us better than R0 structure).
// ===========================================================================
__device__ __forceinline__
void mfma_phase32(const short* As, const short* __restrict__ Wf,
                  int lane, int w, f4v acc[2][2])
{
    s8v bv[2][4];
#pragma unroll
    for (int nt2 = 0; nt2 < 2; ++nt2)
#pragma unroll
        for (int kc = 0; kc < 4; ++kc)
            bv[nt2][kc] = *(const s8v*)(Wf + (((2 * w + nt2) * 4 + kc) * 64 + lane) * 8);
#pragma unroll
    for (int mt = 0; mt < 2; ++mt)
#pragma unroll
        for (int nt2 = 0; nt2 < 2; ++nt2)
            acc[mt][nt2] = (f4v){0.f, 0.f, 0.f, 0.f};
#pragma unroll
    for (int kc = 0; kc < 4; ++kc) {
        const int sl = (lane ^ (kc << 1)) * 8;
        s8v a0 = *(const s8v*)&As[(0 * 4 + kc) * 512 + sl];
        s8v a1 = *(const s8v*)&As[(1 * 4 + kc) * 512 + sl];
#pragma unroll
        for (int nt2 = 0; nt2 < 2; ++nt2) {
            acc[0][nt2] = __builtin_amdgcn_mfma_f32_16x16x32_bf16(a0, bv[nt2][kc], acc[0][nt2], 0, 0, 0);
            acc[1][nt2] = __builtin_amdgcn_mfma_f32_16x16x32_bf16(a1, bv[nt2][kc], acc[1][nt2], 0, 0, 0);
        }
    }
}

__device__ __forceinline__
void c_to_lds32(float* Cs, int lane, int w, const f4v acc[2][2])
{
#pragma unroll
    for (int mt = 0; mt < 2; ++mt) {
        const int r0 = mt * 16 + (lane >> 4) * 4;
#pragma unroll
        for (int nt2 = 0; nt2 < 2; ++nt2) {
            const int col = w * 32 + nt2 * 16 + (lane & 15);
            const int g = col >> 2, jj = col & 3;
#pragma unroll
            for (int i = 0; i < 4; ++i) {
                const int row = r0 + i;
                const int gs  = g ^ (((row >> 2) & 3) << 2);
                Cs[row * 128 + gs * 4 + jj] = acc[mt][nt2][i];
            }
        }
    }
}

__device__ __forceinline__
void gemm_tile32(int m0, const short* __restrict__ Xb,
                 const short* __restrict__ WtL, const float* __restrict__ bias,
                 short* __restrict__ Kb, unsigned int* __restrict__ QV,
                 float* __restrict__ AggF,
                 short* As, float* Cs, float* biasS)
{
    const int tid  = threadIdx.x;
    const int lane = tid & 63;
    const int w    = tid >> 6;

    if (tid < 128) biasS[tid] = bias[tid];

    // ---- Stage A (32 rows x 128 k, bf16) fragment-major, swizzled ----
#pragma unroll
    for (int i = 0; i < 2; ++i) {
        const int m   = (tid >> 4) + 16 * i;
        const int oct = tid & 15;
        const int row = m0 + m;
        s8v v = (s8v){0, 0, 0, 0, 0, 0, 0, 0};
        if (row < N_NODES)
            v = *(const s8v*)(Xb + (size_t)row * D + oct * 8);
        const int kc = oct >> 2, quad = oct & 3;
        const int frag = (m >> 4) * 4 + kc;
        const int slot = ((m & 15) + 16 * quad) ^ (kc << 1);
        *(s8v*)&As[frag * 512 + slot * 8] = v;
    }

    f4v acc[2][2], accV[2][2];
    __syncthreads();

    // ================= Phase K (sel 0) =================
    mfma_phase32(As, WtL + 0 * W_FRAG_SHORTS, lane, w, acc);
    c_to_lds32(Cs, lane, w, acc);
    __syncthreads();
#pragma unroll
    for (int j = 0; j < 4; ++j) {
        const int c   = tid + 256 * j;
        const int row = c >> 5, gg = c & 31;
        const int gs  = gg ^ (((row >> 2) & 3) << 2);
        const f4v vv  = *(const f4v*)&Cs[row * 128 + gs * 4];
        const int grow = m0 + row;
        if (grow < N_NODES) {
            uint2* kp = (uint2*)((unsigned int*)Kb + (size_t)grow * 64 + gg * 2);
            *kp = make_uint2(packbf(vv[0], vv[1]), packbf(vv[2], vv[3]));
        }
    }
    __syncthreads();

    // ================= Phase QV (sel 1 + 2, joint epilogue) =================
    mfma_phase32(As, WtL + 1 * W_FRAG_SHORTS, lane, w, acc);   // Q
    mfma_phase32(As, WtL + 2 * W_FRAG_SHORTS, lane, w, accV);  // V
    c_to_lds32(Cs, lane, w, acc);        // Q roundtrip
    __syncthreads();
    unsigned int qp0[4], qp1[4];
#pragma unroll
    for (int j = 0; j < 4; ++j) {
        const int c   = tid + 256 * j;
        const int row = c >> 5, gg = c & 31;
        const int gs  = gg ^ (((row >> 2) & 3) << 2);
        const f4v vv  = *(const f4v*)&Cs[row * 128 + gs * 4];
        qp0[j] = packbf(vv[0], vv[1]);
        qp1[j] = packbf(vv[2], vv[3]);
    }
    __syncthreads();
    c_to_lds32(Cs, lane, w, accV);       // V roundtrip
    __syncthreads();
#pragma unroll
    for (int j = 0; j < 4; ++j) {
        const int c   = tid + 256 * j;
        const int row = c >> 5, gg = c & 31;
        const int gs  = gg ^ (((row >> 2) & 3) << 2);
        const f4v vv  = *(const f4v*)&Cs[row * 128 + gs * 4];
        const int grow = m0 + row;
        if (grow < N_NODES) {
            uint4* qvp = (uint4*)(QV + (size_t)grow * 128 + gg * 4);
            *qvp = make_uint4(qp0[j], packbf(vv[0], vv[1]),
                              qp1[j], packbf(vv[2], vv[3]));
        }
    }
    __syncthreads();

    // ================= Phase S (sel 3, skip + bias, fp32 out) ==============
    mfma_phase32(As, WtL + 3 * W_FRAG_SHORTS, lane, w, acc);
    c_to_lds32(Cs, lane, w, acc);
    __syncthreads();
#pragma unroll
    for (int j = 0; j < 4; ++j) {
        const int c   = tid + 256 * j;
        const int row = c >> 5, gg = c & 31;
        const int gs  = gg ^ (((row >> 2) & 3) << 2);
        const f4v vv  = *(const f4v*)&Cs[row * 128 + gs * 4];
        const int grow = m0 + row;
        if (grow >= N_NODES) continue;
        const float4 bv = *(const float4*)&biasS[gg * 4];
        *(float4*)&AggF[(size_t)grow * D + gg * 4] =
            make_float4(vv[0] + bv.x, vv[1] + bv.y, vv[2] + bv.z, vv[3] + bv.w);
    }
}

// ---------------------------------------------------------------------------
// Layer-1 GEMM (R0 structure) + fused edge scatter, scatter blocks FIRST
// (short blocks drain, long GEMM cohort streams behind — no serialized tail).
// ---------------------------------------------------------------------------
__global__ __launch_bounds__(256)
void gemm1_scatter(const float* __restrict__ X, const short* __restrict__ WtL,
                   const float* __restrict__ bias,
                   short* __restrict__ Kb, unsigned int* __restrict__ QV,
                   unsigned int* __restrict__ AggB,
                   const int* __restrict__ src, const int* __restrict__ tgt,
                   int* __restrict__ cursor, int* __restrict__ es)
{
    __shared__ __align__(16) short As[8192];    // 16 KB
    __shared__ __align__(16) short Bs[16384];   // 32 KB (doubles as Cs fp32)
    __shared__ __align__(16) float biasS[128];

    if (blockIdx.x >= HIST_BLOCKS) {
        gemm_tile64((blockIdx.x - HIST_BLOCKS) * 64, X, WtL, bias,
                    Kb, QV, AggB, As, Bs, biasS);
    } else {
        const int e = blockIdx.x * 256 + threadIdx.x;
        if (e < N_EDGES) {
            int pos = atomicAdd(&cursor[tgt[e]], 1);
            es[pos] = src[e];
        }
    }
}

// Layer-2 GEMM (R1 structure; bf16 relu(h) input, fp32 agg -> d_out).
__global__ __launch_bounds__(256, 4)
void gemm2(const short* __restrict__ Hb, const short* __restrict__ WtL,
           const float* __restrict__ bias,
           short* __restrict__ Kb, unsigned int* __restrict__ QV,
           float* __restrict__ AggF)
{
    __shared__ __align__(16) short As[4096];
    __shared__ __align__(16) float Cs[4096];
    __shared__ __align__(16) float biasS[128];
    gemm_tile32(blockIdx.x * 32, Hb, WtL, bias, Kb, QV, AggF, As, Cs, biasS);
}

// ---------------------------------------------------------------------------
// Atomic-free per-node aggregation. One wave per node. 8-wide gather stage.
// ---------------------------------------------------------------------------
template<bool FIRST>
__global__ __launch_bounds__(256)
void node_agg(const int* __restrict__ off, const int* __restrict__ es,
              const short* __restrict__ K, const unsigned int* __restrict__ QV,
              const void* __restrict__ Skip, float* __restrict__ OutF,
              unsigned int* __restrict__ Hb)
{
    const int lane = threadIdx.x & 63;
    const int t    = __builtin_amdgcn_readfirstlane(blockIdx.x * 4 + (threadIdx.x >> 6));

    const unsigned int ku = ((const unsigned int*)K)[(size_t)t * 64 + lane];
    const float kx = bflo(ku), ky = bfhi(ku);

    float skx, sky;
    if (FIRST) {
        const unsigned int su = ((const unsigned int*)Skip)[(size_t)t * 64 + lane];
        skx = bflo(su); sky = bfhi(su);
    } else {
        const float2 s2 = ((const float2*)Skip)[(size_t)t * 64 + lane];
        skx = s2.x; sky = s2.y;
    }

    float ax = 0.f, ay = 0.f, bx = 0.f, by = 0.f;
    const int e0 = __builtin_amdgcn_readfirstlane(off[t]);
    const int e1 = __builtin_amdgcn_readfirstlane(off[t + 1]);

    int e = e0;
    for (; e + 8 <= e1; e += 8) {
        const int sv = es[e + (lane & 7)];
        uint2 g[8];
#pragma unroll
        for (int u = 0; u < 8; ++u) {
            const int s = __builtin_amdgcn_readlane(sv, u);
            g[u] = ((const uint2*)(QV + (size_t)s * 128))[lane];
        }
#pragma unroll
        for (int u = 0; u < 8; ++u) {
            if (u & 1) {
                bx += bflo(g[u].y) * sigm(kx + bflo(g[u].x));
                by += bfhi(g[u].y) * sigm(ky + bfhi(g[u].x));
            } else {
                ax += bflo(g[u].y) * sigm(kx + bflo(g[u].x));
                ay += bfhi(g[u].y) * sigm(ky + bfhi(g[u].x));
            }
        }
    }
    if (e + 4 <= e1) {
        const int sv = es[e + (lane & 3)];
        uint2 g[4];
#pragma unroll
        for (int u = 0; u < 4; ++u) {
            const int s = __builtin_amdgcn_readlane(sv, u);
            g[u] = ((const uint2*)(QV + (size_t)s * 128))[lane];
        }
#pragma unroll
        for (int u = 0; u < 4; ++u) {
            if (u & 1) {
                bx += bflo(g[u].y) * sigm(kx + bflo(g[u].x));
                by += bfhi(g[u].y) * sigm(ky + bfhi(g[u].x));
            } else {
                ax += bflo(g[u].y) * sigm(kx + bflo(g[u].x));
                ay += bfhi(g[u].y) * sigm(ky + bfhi(g[u].x));
            }
        }
        e += 4;
    }
    for (; e < e1; ++e) {
        const int s0 = __builtin_amdgcn_readfirstlane(es[e]);
        const uint2 g0 = ((const uint2*)(QV + (size_t)s0 * 128))[lane];
        ax += bflo(g0.y) * sigm(kx + bflo(g0.x));
        ay += bfhi(g0.y) * sigm(ky + bfhi(g0.x));
    }

    const float rx = skx + ax + bx;
    const float ry = sky + ay + by;

    if (FIRST) {
        Hb[(size_t)t * 64 + lane] = packbf(fmaxf(rx, 0.f), fmaxf(ry, 0.f));
    } else {
        ((float2*)OutF)[(size_t)t * 64 + lane] = make_float2(rx, ry);
    }
}

extern "C" void kernel_launch(void* const* d_in, const int* in_sizes, int n_in,
                              void* d_out, int out_size, void* d_ws, size_t ws_size,
                              hipStream_t stream)
{
    const float* x   = (const float*)d_in[0];
    const int*   ei  = (const int*)d_in[1];
    const float* Wk1 = (const float*)d_in[2];
    const float* Wq1 = (const float*)d_in[3];
    const float* Wv1 = (const float*)d_in[4];
    const float* Ws1 = (const float*)d_in[5];
    const float* b1  = (const float*)d_in[6];
    const float* Wk2 = (const float*)d_in[7];
    const float* Wq2 = (const float*)d_in[8];
    const float* Wv2 = (const float*)d_in[9];
    const float* Ws2 = (const float*)d_in[10];
    const float* b2  = (const float*)d_in[11];

    const int* src = ei;
    const int* tgt = ei + N_EDGES;

    const size_t nd = (size_t)N_NODES * D;   // 6.4M elements
    short* kb   = (short*)d_ws;              // bf16 K                (nd shorts)
    short* qv   = kb + nd;                   // bf16 QV interleaved   (2*nd)
    short* hb   = qv + 2 * nd;               // bf16 relu(h)          (nd)
    short* ag1  = hb + nd;                   // bf16 x@Ws1+b1         (nd)
    short* wt   = ag1 + nd;                  // 8 * 16384 shorts
    int* counts    = (int*)(wt + 8 * W_FRAG_SHORTS);   // N_NODES
    int* done_ctr  = counts + N_NODES;                 // 1 (+1 pad)
    int* off       = counts + N_NODES + 2;             // N_NODES + 1
    int* cursor    = off + N_NODES + 1;                // N_NODES
    int* es        = cursor + N_NODES;                 // N_EDGES
    int* chunk_sum = es + N_EDGES;                     // NCHUNKS
    float* out = (float*)d_out;

    hipMemsetAsync(counts, 0, (N_NODES + 2) * sizeof(int), stream);
    prep_all<<<PREP_BLOCKS, 256, 0, stream>>>(Wk1, Wq1, Wv1, Ws1, Wk2, Wq2, Wv2, Ws2,
                                              wt, tgt, counts);
    csr_scan<<<NCHUNKS, 256, 0, stream>>>(counts, off, cursor, done_ctr, chunk_sum);

    // Layer 1 (+ fused edge scatter, scatter blocks first)
    gemm1_scatter<<<HIST_BLOCKS + NBLK64, 256, 0, stream>>>(
        x, wt, b1, kb, (unsigned int*)qv, (unsigned int*)ag1, src, tgt, cursor, es);
    node_agg<true><<<N_NODES / 4, 256, 0, stream>>>(off, es, kb, (const unsigned int*)qv,
                                                    ag1, nullptr, (unsigned int*)hb);

    // Layer 2
    gemm2<<<NBLK32, 256, 0, stream>>>(hb, wt + 4 * W_FRAG_SHORTS, b2,
                                      kb, (unsigned int*)qv, out);
    node_agg<false><<<N_NODES / 4, 256, 0, stream>>>(off, es, kb, (const unsigned int*)qv,
                                                     out, out, nullptr);
}

// Round 8
// 249.462 us; speedup vs baseline: 1.0951x; 1.0510x over previous
//
#include <hip/hip_runtime.h>

#define N_NODES 50000
#define D 128
#define N_EDGES 400000
#define NCHUNKS ((N_NODES + 255) / 256)   // 196
#define NBLK64 ((N_NODES + 63) / 64)      // 782
#define W_FRAG_SHORTS 16384               // 32 frags * 64 lanes * 8 bf16 per weight

#define MW_BLOCKS  64                     // 8 weights * 8 slot-blocks
#define HIST_BLOCKS ((N_EDGES + 255) / 256)   // 1563
#define PREP_BLOCKS (MW_BLOCKS + HIST_BLOCKS)

typedef short s8v  __attribute__((ext_vector_type(8)));   // 8 bf16 (4 VGPRs)
typedef float f4v  __attribute__((ext_vector_type(4)));   // MFMA accumulator
typedef float f2v  __attribute__((ext_vector_type(2)));   // fp8 cvt result

__device__ __forceinline__ unsigned int f2bf(float f) {
    unsigned int u = __float_as_uint(f);
    u += 0x7FFFu + ((u >> 16) & 1u);
    return u >> 16;
}
__device__ __forceinline__ unsigned int packbf(float a, float b) {
    return (f2bf(b) << 16) | f2bf(a);
}
__device__ __forceinline__ float bflo(unsigned int u) { return __uint_as_float(u << 16); }
__device__ __forceinline__ float bfhi(unsigned int u) { return __uint_as_float(u & 0xFFFF0000u); }
__device__ __forceinline__ float sigm(float x) {
    return __builtin_amdgcn_rcpf(1.f + __expf(-x));   // v_rcp_f32, ~1 ulp
}
// pack 2 f32 -> 2 OCP e4m3 bytes in bits [15:0]
__device__ __forceinline__ unsigned int pk8(float a, float b) {
    return (unsigned int)__builtin_amdgcn_cvt_pk_fp8_f32(a, b, 0, false);
}

// ---------------------------------------------------------------------------
// Prep: [0,MW) weight frags | [MW, ...) tgt histogram.
// ---------------------------------------------------------------------------
__global__ __launch_bounds__(256)
void prep_all(const float* __restrict__ W0, const float* __restrict__ W1,
              const float* __restrict__ W2, const float* __restrict__ W3,
              const float* __restrict__ W4, const float* __restrict__ W5,
              const float* __restrict__ W6, const float* __restrict__ W7,
              short* __restrict__ Wt,
              const int* __restrict__ tgt, int* __restrict__ counts)
{
    const int b = blockIdx.x;
    if (b < MW_BLOCKS) {
        const int wsel = b >> 3;
        const float* W = (wsel == 0) ? W0 : (wsel == 1) ? W1 : (wsel == 2) ? W2 :
                         (wsel == 3) ? W3 : (wsel == 4) ? W4 : (wsel == 5) ? W5 :
                         (wsel == 6) ? W6 : W7;
        const int slot = (b & 7) * 256 + threadIdx.x;
        const int frag = slot >> 6;
        const int lane = slot & 63;
        const int n    = (frag >> 2) * 16 + (lane & 15);
        const int kc   = frag & 3;
        const int quad = lane >> 4;
        const int k0   = kc * 32 + quad * 8;
        s8v v;
#pragma unroll
        for (int j = 0; j < 8; ++j)
            v[j] = (short)f2bf(W[(size_t)(k0 + j) * D + n]);
        *(s8v*)(Wt + (size_t)wsel * W_FRAG_SHORTS + (size_t)slot * 8) = v;
    } else {
        const int e = (b - MW_BLOCKS) * 256 + threadIdx.x;
        if (e < N_EDGES) atomicAdd(&counts[tgt[e]], 1);
    }
}

// ---------------------------------------------------------------------------
// Single-kernel CSR offset build (R8-verified).
// ---------------------------------------------------------------------------
__global__ __launch_bounds__(256)
void csr_scan(const int* __restrict__ counts, int* __restrict__ off,
              int* __restrict__ cursor, int* __restrict__ done_ctr,
              int* __restrict__ chunk_sum)
{
    __shared__ int s[256];
    const int b = blockIdx.x, t = threadIdx.x;
    const int i = b * 256 + t;
    const int v = (i < N_NODES) ? counts[i] : 0;
    s[t] = v;
    __syncthreads();
    for (int d = 1; d < 256; d <<= 1) {
        int tt = (t >= d) ? s[t - d] : 0;
        __syncthreads();
        s[t] += tt;
        __syncthreads();
    }
    const int incl = s[t];

    if (t == 255) {
        __hip_atomic_store(&chunk_sum[b], incl, __ATOMIC_RELAXED, __HIP_MEMORY_SCOPE_AGENT);
        __hip_atomic_fetch_add(done_ctr, 1, __ATOMIC_RELEASE, __HIP_MEMORY_SCOPE_AGENT);
    }
    if (t == 0) {
        while (__hip_atomic_load(done_ctr, __ATOMIC_ACQUIRE, __HIP_MEMORY_SCOPE_AGENT) < NCHUNKS)
            __builtin_amdgcn_s_sleep(8);
    }
    __syncthreads();

    const int pv = (t < b) ? __hip_atomic_load(&chunk_sum[t], __ATOMIC_RELAXED,
                                               __HIP_MEMORY_SCOPE_AGENT) : 0;
    __syncthreads();
    s[t] = pv;
    __syncthreads();
    for (int d = 128; d > 0; d >>= 1) {
        if (t < d) s[t] += s[t + d];
        __syncthreads();
    }
    const int base = s[0];

    if (i < N_NODES) {
        const int excl = base + incl - v;
        off[i]    = excl;
        cursor[i] = excl;
    }
    if (b == 0 && t == 0) off[N_NODES] = N_EDGES;
}

// ---------------------------------------------------------------------------
// gemm_tile building blocks (R0 structure, unchanged).
// ---------------------------------------------------------------------------
__device__ __forceinline__
void stage_b(const short* __restrict__ Wf, short* Bs, int tid)
{
#pragma unroll
    for (int j = 0; j < 8; ++j) {
        const int chunk = tid + 256 * j;
        __builtin_amdgcn_global_load_lds(
            (const __attribute__((address_space(1))) unsigned int*)(Wf + chunk * 8),
            (__attribute__((address_space(3))) unsigned int*)(&Bs[(chunk & ~63) * 8]),
            16, 0, 0);
    }
}

__device__ __forceinline__
void mfma_phase(const short* As, const short* Bs, int lane, int wr, int wc,
                f4v acc[2][4])
{
#pragma unroll
    for (int mt = 0; mt < 2; ++mt)
#pragma unroll
        for (int nt = 0; nt < 4; ++nt)
            acc[mt][nt] = (f4v){0.f, 0.f, 0.f, 0.f};
#pragma unroll
    for (int kc = 0; kc < 4; ++kc) {
        const int sl = (lane ^ (kc << 1)) * 8;
        s8v a0 = *(const s8v*)&As[((2 * wr + 0) * 4 + kc) * 512 + sl];
        s8v a1 = *(const s8v*)&As[((2 * wr + 1) * 4 + kc) * 512 + sl];
#pragma unroll
        for (int nt = 0; nt < 4; ++nt) {
            s8v b = *(const s8v*)&Bs[((4 * wc + nt) * 4 + kc) * 512 + lane * 8];
            acc[0][nt] = __builtin_amdgcn_mfma_f32_16x16x32_bf16(a0, b, acc[0][nt], 0, 0, 0);
            acc[1][nt] = __builtin_amdgcn_mfma_f32_16x16x32_bf16(a1, b, acc[1][nt], 0, 0, 0);
        }
    }
}

__device__ __forceinline__
void c_to_lds(float* Cs, int lane, int wr, int wc, const f4v acc[2][4])
{
#pragma unroll
    for (int mt = 0; mt < 2; ++mt) {
        const int r0 = wr * 32 + mt * 16 + (lane >> 4) * 4;
#pragma unroll
        for (int nt = 0; nt < 4; ++nt) {
            const int col = wc * 64 + nt * 16 + (lane & 15);
            const int g = col >> 2, jj = col & 3;
#pragma unroll
            for (int i = 0; i < 4; ++i) {
                const int row = r0 + i;
                const int gs  = g ^ (((row >> 2) & 3) << 2);
                Cs[row * 128 + gs * 4 + jj] = acc[mt][nt][i];
            }
        }
    }
}

// ---------------------------------------------------------------------------
// Fused 4-projection GEMM tile: 64 rows, phases K | QV-joint | S.
// Q epilogue packs fp8-e4m3 (node-major, 128B/node): thread (row,gg) writes
// one dword = fp8{q(4gg..4gg+3)} at Q8[row*32+gg]; lane l in node_agg reads
// ushort (dims 2l,2l+1). V stays bf16 (256B/node) — its error enters the
// edge-sum linearly, while Q's is sigmoid-attenuated (R6 post-mortem).
// ---------------------------------------------------------------------------
template<bool X_FP32, bool AGG_BF16>
__device__ __forceinline__
void gemm_tile(int m0, const float* __restrict__ Xf, const short* __restrict__ Xb,
               const short* __restrict__ WtL, const float* __restrict__ bias,
               short* __restrict__ Kb, unsigned int* __restrict__ Q8,
               unsigned int* __restrict__ Vw,
               float* __restrict__ AggF, unsigned int* __restrict__ AggB,
               short* As, short* Bs, float* biasS)
{
    const int tid  = threadIdx.x;
    const int lane = tid & 63;
    const int w    = tid >> 6;
    const int wr   = w & 1;
    const int wc   = w >> 1;

    if (tid < 128) biasS[tid] = bias[tid];

    // ---- Stage A (64 rows x 128 k, bf16) fragment-major, swizzled ----
#pragma unroll
    for (int i = 0; i < 4; ++i) {
        const int m   = (tid >> 4) + 16 * i;
        const int oct = tid & 15;
        const int row = m0 + m;
        s8v v = (s8v){0, 0, 0, 0, 0, 0, 0, 0};
        if (row < N_NODES) {
            if (X_FP32) {
                const float* p = Xf + (size_t)row * D + oct * 8;
                float4 a0 = *(const float4*)p;
                float4 a1 = *(const float4*)(p + 4);
                v[0] = (short)f2bf(a0.x); v[1] = (short)f2bf(a0.y);
                v[2] = (short)f2bf(a0.z); v[3] = (short)f2bf(a0.w);
                v[4] = (short)f2bf(a1.x); v[5] = (short)f2bf(a1.y);
                v[6] = (short)f2bf(a1.z); v[7] = (short)f2bf(a1.w);
            } else {
                v = *(const s8v*)(Xb + (size_t)row * D + oct * 8);
            }
        }
        const int kc = oct >> 2, quad = oct & 3;
        const int frag = (m >> 4) * 4 + kc;
        const int slot = ((m & 15) + 16 * quad) ^ (kc << 1);
        *(s8v*)&As[frag * 512 + slot * 8] = v;
    }

    float* Cs = (float*)Bs;
    f4v acc[2][4];

    // ================= Phase K (sel 0) =================
    __syncthreads();
    stage_b(WtL + 0 * W_FRAG_SHORTS, Bs, tid);
    __syncthreads();
    mfma_phase(As, Bs, lane, wr, wc, acc);
    __syncthreads();
    c_to_lds(Cs, lane, wr, wc, acc);
    __syncthreads();
#pragma unroll
    for (int j = 0; j < 8; ++j) {
        const int c   = tid + 256 * j;
        const int row = c >> 5, gg = c & 31;
        const int gs  = gg ^ (((row >> 2) & 3) << 2);
        const f4v vv  = *(const f4v*)&Cs[row * 128 + gs * 4];
        const int grow = m0 + row;
        if (grow < N_NODES) {
            uint2* kp = (uint2*)((unsigned int*)Kb + (size_t)grow * 64 + gg * 2);
            *kp = make_uint2(packbf(vv[0], vv[1]), packbf(vv[2], vv[3]));
        }
    }

    // ================= Phase QV (sel 1 + 2, Q-fp8/V-bf16 epilogue) =========
    f4v accV[2][4];
    __syncthreads();                       // Cs readers done
    stage_b(WtL + 1 * W_FRAG_SHORTS, Bs, tid);
    __syncthreads();
    mfma_phase(As, Bs, lane, wr, wc, acc);  // Q
    __syncthreads();
    stage_b(WtL + 2 * W_FRAG_SHORTS, Bs, tid);
    __syncthreads();
    mfma_phase(As, Bs, lane, wr, wc, accV); // V
    __syncthreads();
    c_to_lds(Cs, lane, wr, wc, acc);        // Q roundtrip
    __syncthreads();
    unsigned int qw[8];
#pragma unroll
    for (int j = 0; j < 8; ++j) {
        const int c   = tid + 256 * j;
        const int row = c >> 5, gg = c & 31;
        const int gs  = gg ^ (((row >> 2) & 3) << 2);
        const f4v vv  = *(const f4v*)&Cs[row * 128 + gs * 4];
        qw[j] = pk8(vv[0], vv[1]) | (pk8(vv[2], vv[3]) << 16);
    }
    __syncthreads();
    c_to_lds(Cs, lane, wr, wc, accV);       // V roundtrip
    __syncthreads();
#pragma unroll
    for (int j = 0; j < 8; ++j) {
        const int c   = tid + 256 * j;
        const int row = c >> 5, gg = c & 31;
        const int gs  = gg ^ (((row >> 2) & 3) << 2);
        const f4v vv  = *(const f4v*)&Cs[row * 128 + gs * 4];
        const int grow = m0 + row;
        if (grow < N_NODES) {
            Q8[(size_t)grow * 32 + gg] = qw[j];
            uint2* vp = (uint2*)(Vw + (size_t)grow * 64 + gg * 2);
            *vp = make_uint2(packbf(vv[0], vv[1]), packbf(vv[2], vv[3]));
        }
    }

    // ================= Phase S (sel 3, skip + bias) =================
    __syncthreads();
    stage_b(WtL + 3 * W_FRAG_SHORTS, Bs, tid);
    __syncthreads();
    mfma_phase(As, Bs, lane, wr, wc, acc);
    __syncthreads();
    c_to_lds(Cs, lane, wr, wc, acc);
    __syncthreads();
#pragma unroll
    for (int j = 0; j < 8; ++j) {
        const int c   = tid + 256 * j;
        const int row = c >> 5, gg = c & 31;
        const int gs  = gg ^ (((row >> 2) & 3) << 2);
        const f4v vv  = *(const f4v*)&Cs[row * 128 + gs * 4];
        const int grow = m0 + row;
        if (grow >= N_NODES) continue;
        const float4 bv = *(const float4*)&biasS[gg * 4];
        const float o0 = vv[0] + bv.x, o1 = vv[1] + bv.y;
        const float o2 = vv[2] + bv.z, o3 = vv[3] + bv.w;
        if (AGG_BF16) {
            uint2* ap = (uint2*)(AggB + (size_t)grow * 64 + gg * 2);
            *ap = make_uint2(packbf(o0, o1), packbf(o2, o3));
        } else {
            *(float4*)&AggF[(size_t)grow * D + gg * 4] = make_float4(o0, o1, o2, o3);
        }
    }
}

// ---------------------------------------------------------------------------
// Layer-1 GEMM (fp32 x input, bf16 agg out) + fused edge scatter blocks
// (R0 ordering: gemm blocks first, scatter after — measured best).
// ---------------------------------------------------------------------------
__global__ __launch_bounds__(256)
void gemm1_scatter(const float* __restrict__ X, const short* __restrict__ WtL,
                   const float* __restrict__ bias,
                   short* __restrict__ Kb, unsigned int* __restrict__ Q8,
                   unsigned int* __restrict__ Vw,
                   unsigned int* __restrict__ AggB,
                   const int* __restrict__ src, const int* __restrict__ tgt,
                   int* __restrict__ cursor, int* __restrict__ es)
{
    __shared__ __align__(16) short As[8192];    // 16 KB
    __shared__ __align__(16) short Bs[16384];   // 32 KB (doubles as Cs fp32)
    __shared__ __align__(16) float biasS[128];

    if (blockIdx.x < NBLK64) {
        gemm_tile<true, true>(blockIdx.x * 64, X, nullptr, WtL, bias,
                              Kb, Q8, Vw, nullptr, AggB, As, Bs, biasS);
    } else {
        const int e = (blockIdx.x - NBLK64) * 256 + threadIdx.x;
        if (e < N_EDGES) {
            int pos = atomicAdd(&cursor[tgt[e]], 1);
            es[pos] = src[e];
        }
    }
}

// Layer-2 GEMM (bf16 relu(h) input, fp32 agg -> d_out).
__global__ __launch_bounds__(256)
void gemm2(const short* __restrict__ Hb, const short* __restrict__ WtL,
           const float* __restrict__ bias,
           short* __restrict__ Kb, unsigned int* __restrict__ Q8,
           unsigned int* __restrict__ Vw,
           float* __restrict__ AggF)
{
    __shared__ __align__(16) short As[8192];
    __shared__ __align__(16) short Bs[16384];
    __shared__ __align__(16) float biasS[128];
    gemm_tile<false, false>(blockIdx.x * 64, nullptr, Hb, WtL, bias,
                            Kb, Q8, Vw, AggF, nullptr, As, Bs, biasS);
}

// ---------------------------------------------------------------------------
// Atomic-free per-node aggregation. One wave per node. 8-wide gather stage:
// per edge, lane reads ushort Q-fp8 (dims 2l,2l+1) + uint V-bf16 — 384B/edge
// (was 512B). Unpack Q with v_cvt_pk_f32_fp8.
// FIRST: Skip = bf16 agg1; out = bf16 relu -> Hb. Else: Skip = fp32 (d_out RMW).
// ---------------------------------------------------------------------------
template<bool FIRST>
__global__ __launch_bounds__(256)
void node_agg(const int* __restrict__ off, const int* __restrict__ es,
              const short* __restrict__ K, const unsigned short* __restrict__ Q8s,
              const unsigned int* __restrict__ Vw,
              const void* __restrict__ Skip, float* __restrict__ OutF,
              unsigned int* __restrict__ Hb)
{
    const int lane = threadIdx.x & 63;
    const int t    = __builtin_amdgcn_readfirstlane(blockIdx.x * 4 + (threadIdx.x >> 6));

    const unsigned int ku = ((const unsigned int*)K)[(size_t)t * 64 + lane];
    const float kx = bflo(ku), ky = bfhi(ku);

    float skx, sky;
    if (FIRST) {
        const unsigned int su = ((const unsigned int*)Skip)[(size_t)t * 64 + lane];
        skx = bflo(su); sky = bfhi(su);
    } else {
        const float2 s2 = ((const float2*)Skip)[(size_t)t * 64 + lane];
        skx = s2.x; sky = s2.y;
    }

    float ax = 0.f, ay = 0.f, bx = 0.f, by = 0.f;
    const int e0 = __builtin_amdgcn_readfirstlane(off[t]);
    const int e1 = __builtin_amdgcn_readfirstlane(off[t + 1]);

    int e = e0;
    for (; e + 8 <= e1; e += 8) {
        const int sv = es[e + (lane & 7)];
        unsigned int gq[8], gv[8];
#pragma unroll
        for (int u = 0; u < 8; ++u) {
            const int s = __builtin_amdgcn_readlane(sv, u);
            gq[u] = Q8s[(size_t)s * 64 + lane];
            gv[u] = Vw[(size_t)s * 64 + lane];
        }
#pragma unroll
        for (int u = 0; u < 8; ++u) {
            const f2v qp = __builtin_amdgcn_cvt_pk_f32_fp8(gq[u], false);
            if (u & 1) {
                bx += bflo(gv[u]) * sigm(kx + qp[0]);
                by += bfhi(gv[u]) * sigm(ky + qp[1]);
            } else {
                ax += bflo(gv[u]) * sigm(kx + qp[0]);
                ay += bfhi(gv[u]) * sigm(ky + qp[1]);
            }
        }
    }
    if (e + 4 <= e1) {
        const int sv = es[e + (lane & 3)];
        unsigned int gq[4], gv[4];
#pragma unroll
        for (int u = 0; u < 4; ++u) {
            const int s = __builtin_amdgcn_readlane(sv, u);
            gq[u] = Q8s[(size_t)s * 64 + lane];
            gv[u] = Vw[(size_t)s * 64 + lane];
        }
#pragma unroll
        for (int u = 0; u < 4; ++u) {
            const f2v qp = __builtin_amdgcn_cvt_pk_f32_fp8(gq[u], false);
            if (u & 1) {
                bx += bflo(gv[u]) * sigm(kx + qp[0]);
                by += bfhi(gv[u]) * sigm(ky + qp[1]);
            } else {
                ax += bflo(gv[u]) * sigm(kx + qp[0]);
                ay += bfhi(gv[u]) * sigm(ky + qp[1]);
            }
        }
        e += 4;
    }
    for (; e < e1; ++e) {
        const int s0 = __builtin_amdgcn_readfirstlane(es[e]);
        const unsigned int gq = Q8s[(size_t)s0 * 64 + lane];
        const unsigned int gv = Vw[(size_t)s0 * 64 + lane];
        const f2v qp = __builtin_amdgcn_cvt_pk_f32_fp8(gq, false);
        ax += bflo(gv) * sigm(kx + qp[0]);
        ay += bfhi(gv) * sigm(ky + qp[1]);
    }

    const float rx = skx + ax + bx;
    const float ry = sky + ay + by;

    if (FIRST) {
        Hb[(size_t)t * 64 + lane] = packbf(fmaxf(rx, 0.f), fmaxf(ry, 0.f));
    } else {
        ((float2*)OutF)[(size_t)t * 64 + lane] = make_float2(rx, ry);
    }
}

extern "C" void kernel_launch(void* const* d_in, const int* in_sizes, int n_in,
                              void* d_out, int out_size, void* d_ws, size_t ws_size,
                              hipStream_t stream)
{
    const float* x   = (const float*)d_in[0];
    const int*   ei  = (const int*)d_in[1];
    const float* Wk1 = (const float*)d_in[2];
    const float* Wq1 = (const float*)d_in[3];
    const float* Wv1 = (const float*)d_in[4];
    const float* Ws1 = (const float*)d_in[5];
    const float* b1  = (const float*)d_in[6];
    const float* Wk2 = (const float*)d_in[7];
    const float* Wq2 = (const float*)d_in[8];
    const float* Wv2 = (const float*)d_in[9];
    const float* Ws2 = (const float*)d_in[10];
    const float* b2  = (const float*)d_in[11];

    const int* src = ei;
    const int* tgt = ei + N_EDGES;

    const size_t nd = (size_t)N_NODES * D;   // 6.4M elements
    short* kb         = (short*)d_ws;                 // bf16 K        (nd shorts, 12.8MB)
    unsigned int* q8  = (unsigned int*)(kb + nd);     // fp8 Q         (nd/4 uints, 6.4MB)
    short* vb         = (short*)(q8 + nd / 4);        // bf16 V        (nd shorts, 12.8MB)
    short* hb         = vb + nd;                      // bf16 relu(h)  (nd)
    short* ag1        = hb + nd;                      // bf16 x@Ws1+b1 (nd)
    short* wt         = ag1 + nd;                     // 8 * 16384 shorts
    int* counts    = (int*)(wt + 8 * W_FRAG_SHORTS);   // N_NODES
    int* done_ctr  = counts + N_NODES;                 // 1 (+1 pad)
    int* off       = counts + N_NODES + 2;             // N_NODES + 1
    int* cursor    = off + N_NODES + 1;                // N_NODES
    int* es        = cursor + N_NODES;                 // N_EDGES
    int* chunk_sum = es + N_EDGES;                     // NCHUNKS
    float* out = (float*)d_out;

    hipMemsetAsync(counts, 0, (N_NODES + 2) * sizeof(int), stream);
    prep_all<<<PREP_BLOCKS, 256, 0, stream>>>(Wk1, Wq1, Wv1, Ws1, Wk2, Wq2, Wv2, Ws2,
                                              wt, tgt, counts);
    csr_scan<<<NCHUNKS, 256, 0, stream>>>(counts, off, cursor, done_ctr, chunk_sum);

    // Layer 1 (+ fused edge scatter)
    gemm1_scatter<<<NBLK64 + HIST_BLOCKS, 256, 0, stream>>>(
        x, wt, b1, kb, q8, (unsigned int*)vb, (unsigned int*)ag1, src, tgt, cursor, es);
    node_agg<true><<<N_NODES / 4, 256, 0, stream>>>(
        off, es, kb, (const unsigned short*)q8, (const unsigned int*)vb,
        ag1, nullptr, (unsigned int*)hb);

    // Layer 2
    gemm2<<<NBLK64, 256, 0, stream>>>(hb, wt + 4 * W_FRAG_SHORTS, b2,
                                      kb, q8, (unsigned int*)vb, out);
    node_agg<false><<<N_NODES / 4, 256, 0, stream>>>(
        off, es, kb, (const unsigned short*)q8, (const unsigned int*)vb,
        out, out, nullptr);
}

// Round 9
// 246.252 us; speedup vs baseline: 1.1093x; 1.0130x over previous
//
#include <hip/hip_runtime.h>

#define N_NODES 50000
#define D 128
#define N_EDGES 400000
#define NCHUNKS ((N_NODES + 255) / 256)   // 196
#define NBLK64 ((N_NODES + 63) / 64)      // 782
#define W_FRAG_SHORTS 16384               // 32 frags * 64 lanes * 8 bf16 per weight
#define QV_STRIDE 96                      // dwords per node: 32 fp8-Q + 64 bf16-V (384B)

#define MW_BLOCKS  64                     // 8 weights * 8 slot-blocks
#define HIST_BLOCKS ((N_EDGES + 255) / 256)   // 1563
#define PREP_BLOCKS (MW_BLOCKS + HIST_BLOCKS)

typedef short s8v  __attribute__((ext_vector_type(8)));   // 8 bf16 (4 VGPRs)
typedef float f4v  __attribute__((ext_vector_type(4)));   // MFMA accumulator
typedef float f2v  __attribute__((ext_vector_type(2)));   // fp8 cvt result

__device__ __forceinline__ unsigned int f2bf(float f) {
    unsigned int u = __float_as_uint(f);
    u += 0x7FFFu + ((u >> 16) & 1u);
    return u >> 16;
}
__device__ __forceinline__ unsigned int packbf(float a, float b) {
    return (f2bf(b) << 16) | f2bf(a);
}
__device__ __forceinline__ float bflo(unsigned int u) { return __uint_as_float(u << 16); }
__device__ __forceinline__ float bfhi(unsigned int u) { return __uint_as_float(u & 0xFFFF0000u); }
__device__ __forceinline__ float sigm(float x) {
    return __builtin_amdgcn_rcpf(1.f + __expf(-x));   // v_rcp_f32, ~1 ulp
}
// pack 2 f32 -> 2 OCP e4m3 bytes in bits [15:0]
__device__ __forceinline__ unsigned int pk8(float a, float b) {
    return (unsigned int)__builtin_amdgcn_cvt_pk_fp8_f32(a, b, 0, false);
}

// ---------------------------------------------------------------------------
// Prep: [0,MW) weight frags | [MW, ...) tgt histogram.
// ---------------------------------------------------------------------------
__global__ __launch_bounds__(256)
void prep_all(const float* __restrict__ W0, const float* __restrict__ W1,
              const float* __restrict__ W2, const float* __restrict__ W3,
              const float* __restrict__ W4, const float* __restrict__ W5,
              const float* __restrict__ W6, const float* __restrict__ W7,
              short* __restrict__ Wt,
              const int* __restrict__ tgt, int* __restrict__ counts)
{
    const int b = blockIdx.x;
    if (b < MW_BLOCKS) {
        const int wsel = b >> 3;
        const float* W = (wsel == 0) ? W0 : (wsel == 1) ? W1 : (wsel == 2) ? W2 :
                         (wsel == 3) ? W3 : (wsel == 4) ? W4 : (wsel == 5) ? W5 :
                         (wsel == 6) ? W6 : W7;
        const int slot = (b & 7) * 256 + threadIdx.x;
        const int frag = slot >> 6;
        const int lane = slot & 63;
        const int n    = (frag >> 2) * 16 + (lane & 15);
        const int kc   = frag & 3;
        const int quad = lane >> 4;
        const int k0   = kc * 32 + quad * 8;
        s8v v;
#pragma unroll
        for (int j = 0; j < 8; ++j)
            v[j] = (short)f2bf(W[(size_t)(k0 + j) * D + n]);
        *(s8v*)(Wt + (size_t)wsel * W_FRAG_SHORTS + (size_t)slot * 8) = v;
    } else {
        const int e = (b - MW_BLOCKS) * 256 + threadIdx.x;
        if (e < N_EDGES) atomicAdd(&counts[tgt[e]], 1);
    }
}

// ---------------------------------------------------------------------------
// Single-kernel CSR offset build (R8-verified).
// ---------------------------------------------------------------------------
__global__ __launch_bounds__(256)
void csr_scan(const int* __restrict__ counts, int* __restrict__ off,
              int* __restrict__ cursor, int* __restrict__ done_ctr,
              int* __restrict__ chunk_sum)
{
    __shared__ int s[256];
    const int b = blockIdx.x, t = threadIdx.x;
    const int i = b * 256 + t;
    const int v = (i < N_NODES) ? counts[i] : 0;
    s[t] = v;
    __syncthreads();
    for (int d = 1; d < 256; d <<= 1) {
        int tt = (t >= d) ? s[t - d] : 0;
        __syncthreads();
        s[t] += tt;
        __syncthreads();
    }
    const int incl = s[t];

    if (t == 255) {
        __hip_atomic_store(&chunk_sum[b], incl, __ATOMIC_RELAXED, __HIP_MEMORY_SCOPE_AGENT);
        __hip_atomic_fetch_add(done_ctr, 1, __ATOMIC_RELEASE, __HIP_MEMORY_SCOPE_AGENT);
    }
    if (t == 0) {
        while (__hip_atomic_load(done_ctr, __ATOMIC_ACQUIRE, __HIP_MEMORY_SCOPE_AGENT) < NCHUNKS)
            __builtin_amdgcn_s_sleep(8);
    }
    __syncthreads();

    const int pv = (t < b) ? __hip_atomic_load(&chunk_sum[t], __ATOMIC_RELAXED,
                                               __HIP_MEMORY_SCOPE_AGENT) : 0;
    __syncthreads();
    s[t] = pv;
    __syncthreads();
    for (int d = 128; d > 0; d >>= 1) {
        if (t < d) s[t] += s[t + d];
        __syncthreads();
    }
    const int base = s[0];

    if (i < N_NODES) {
        const int excl = base + incl - v;
        off[i]    = excl;
        cursor[i] = excl;
    }
    if (b == 0 && t == 0) off[N_NODES] = N_EDGES;
}

// ---------------------------------------------------------------------------
// gemm_tile building blocks (R0 structure, unchanged).
// ---------------------------------------------------------------------------
__device__ __forceinline__
void stage_b(const short* __restrict__ Wf, short* Bs, int tid)
{
#pragma unroll
    for (int j = 0; j < 8; ++j) {
        const int chunk = tid + 256 * j;
        __builtin_amdgcn_global_load_lds(
            (const __attribute__((address_space(1))) unsigned int*)(Wf + chunk * 8),
            (__attribute__((address_space(3))) unsigned int*)(&Bs[(chunk & ~63) * 8]),
            16, 0, 0);
    }
}

__device__ __forceinline__
void mfma_phase(const short* As, const short* Bs, int lane, int wr, int wc,
                f4v acc[2][4])
{
#pragma unroll
    for (int mt = 0; mt < 2; ++mt)
#pragma unroll
        for (int nt = 0; nt < 4; ++nt)
            acc[mt][nt] = (f4v){0.f, 0.f, 0.f, 0.f};
#pragma unroll
    for (int kc = 0; kc < 4; ++kc) {
        const int sl = (lane ^ (kc << 1)) * 8;
        s8v a0 = *(const s8v*)&As[((2 * wr + 0) * 4 + kc) * 512 + sl];
        s8v a1 = *(const s8v*)&As[((2 * wr + 1) * 4 + kc) * 512 + sl];
#pragma unroll
        for (int nt = 0; nt < 4; ++nt) {
            s8v b = *(const s8v*)&Bs[((4 * wc + nt) * 4 + kc) * 512 + lane * 8];
            acc[0][nt] = __builtin_amdgcn_mfma_f32_16x16x32_bf16(a0, b, acc[0][nt], 0, 0, 0);
            acc[1][nt] = __builtin_amdgcn_mfma_f32_16x16x32_bf16(a1, b, acc[1][nt], 0, 0, 0);
        }
    }
}

__device__ __forceinline__
void c_to_lds(float* Cs, int lane, int wr, int wc, const f4v acc[2][4])
{
#pragma unroll
    for (int mt = 0; mt < 2; ++mt) {
        const int r0 = wr * 32 + mt * 16 + (lane >> 4) * 4;
#pragma unroll
        for (int nt = 0; nt < 4; ++nt) {
            const int col = wc * 64 + nt * 16 + (lane & 15);
            const int g = col >> 2, jj = col & 3;
#pragma unroll
            for (int i = 0; i < 4; ++i) {
                const int row = r0 + i;
                const int gs  = g ^ (((row >> 2) & 3) << 2);
                Cs[row * 128 + gs * 4 + jj] = acc[mt][nt][i];
            }
        }
    }
}

// ---------------------------------------------------------------------------
// Fused 4-projection GEMM tile: 64 rows, phases K | QV-joint | S.
// QV epilogue writes ONE contiguous 384B record per node (stride 96 dwords):
//   rec[0..31]  = fp8-e4m3 Q (dword gg = q[4gg..4gg+3])
//   rec[32..95] = bf16 V    (dwords 32+2gg = {v4gg,v4gg+1},{v4gg+2,v4gg+3})
// Single store region per row (vs R8's two disjoint buffers) — isolates the
// store-stream hypothesis for R8's gemm1 regression. Math identical to R8.
// ---------------------------------------------------------------------------
template<bool X_FP32, bool AGG_BF16>
__device__ __forceinline__
void gemm_tile(int m0, const float* __restrict__ Xf, const short* __restrict__ Xb,
               const short* __restrict__ WtL, const float* __restrict__ bias,
               short* __restrict__ Kb, unsigned int* __restrict__ QVm,
               float* __restrict__ AggF, unsigned int* __restrict__ AggB,
               short* As, short* Bs, float* biasS)
{
    const int tid  = threadIdx.x;
    const int lane = tid & 63;
    const int w    = tid >> 6;
    const int wr   = w & 1;
    const int wc   = w >> 1;

    if (tid < 128) biasS[tid] = bias[tid];

    // ---- Stage A (64 rows x 128 k, bf16) fragment-major, swizzled ----
#pragma unroll
    for (int i = 0; i < 4; ++i) {
        const int m   = (tid >> 4) + 16 * i;
        const int oct = tid & 15;
        const int row = m0 + m;
        s8v v = (s8v){0, 0, 0, 0, 0, 0, 0, 0};
        if (row < N_NODES) {
            if (X_FP32) {
                const float* p = Xf + (size_t)row * D + oct * 8;
                float4 a0 = *(const float4*)p;
                float4 a1 = *(const float4*)(p + 4);
                v[0] = (short)f2bf(a0.x); v[1] = (short)f2bf(a0.y);
                v[2] = (short)f2bf(a0.z); v[3] = (short)f2bf(a0.w);
                v[4] = (short)f2bf(a1.x); v[5] = (short)f2bf(a1.y);
                v[6] = (short)f2bf(a1.z); v[7] = (short)f2bf(a1.w);
            } else {
                v = *(const s8v*)(Xb + (size_t)row * D + oct * 8);
            }
        }
        const int kc = oct >> 2, quad = oct & 3;
        const int frag = (m >> 4) * 4 + kc;
        const int slot = ((m & 15) + 16 * quad) ^ (kc << 1);
        *(s8v*)&As[frag * 512 + slot * 8] = v;
    }

    float* Cs = (float*)Bs;
    f4v acc[2][4];

    // ================= Phase K (sel 0) =================
    __syncthreads();
    stage_b(WtL + 0 * W_FRAG_SHORTS, Bs, tid);
    __syncthreads();
    mfma_phase(As, Bs, lane, wr, wc, acc);
    __syncthreads();
    c_to_lds(Cs, lane, wr, wc, acc);
    __syncthreads();
#pragma unroll
    for (int j = 0; j < 8; ++j) {
        const int c   = tid + 256 * j;
        const int row = c >> 5, gg = c & 31;
        const int gs  = gg ^ (((row >> 2) & 3) << 2);
        const f4v vv  = *(const f4v*)&Cs[row * 128 + gs * 4];
        const int grow = m0 + row;
        if (grow < N_NODES) {
            uint2* kp = (uint2*)((unsigned int*)Kb + (size_t)grow * 64 + gg * 2);
            *kp = make_uint2(packbf(vv[0], vv[1]), packbf(vv[2], vv[3]));
        }
    }

    // ================= Phase QV (sel 1 + 2, merged-record epilogue) ========
    f4v accV[2][4];
    __syncthreads();                       // Cs readers done
    stage_b(WtL + 1 * W_FRAG_SHORTS, Bs, tid);
    __syncthreads();
    mfma_phase(As, Bs, lane, wr, wc, acc);  // Q
    __syncthreads();
    stage_b(WtL + 2 * W_FRAG_SHORTS, Bs, tid);
    __syncthreads();
    mfma_phase(As, Bs, lane, wr, wc, accV); // V
    __syncthreads();
    c_to_lds(Cs, lane, wr, wc, acc);        // Q roundtrip
    __syncthreads();
    unsigned int qw[8];
#pragma unroll
    for (int j = 0; j < 8; ++j) {
        const int c   = tid + 256 * j;
        const int row = c >> 5, gg = c & 31;
        const int gs  = gg ^ (((row >> 2) & 3) << 2);
        const f4v vv  = *(const f4v*)&Cs[row * 128 + gs * 4];
        qw[j] = pk8(vv[0], vv[1]) | (pk8(vv[2], vv[3]) << 16);
    }
    __syncthreads();
    c_to_lds(Cs, lane, wr, wc, accV);       // V roundtrip
    __syncthreads();
#pragma unroll
    for (int j = 0; j < 8; ++j) {
        const int c   = tid + 256 * j;
        const int row = c >> 5, gg = c & 31;
        const int gs  = gg ^ (((row >> 2) & 3) << 2);
        const f4v vv  = *(const f4v*)&Cs[row * 128 + gs * 4];
        const int grow = m0 + row;
        if (grow < N_NODES) {
            unsigned int* rec = QVm + (size_t)grow * QV_STRIDE;
            rec[gg] = qw[j];
            *(uint2*)(rec + 32 + gg * 2) =
                make_uint2(packbf(vv[0], vv[1]), packbf(vv[2], vv[3]));
        }
    }

    // ================= Phase S (sel 3, skip + bias) =================
    __syncthreads();
    stage_b(WtL + 3 * W_FRAG_SHORTS, Bs, tid);
    __syncthreads();
    mfma_phase(As, Bs, lane, wr, wc, acc);
    __syncthreads();
    c_to_lds(Cs, lane, wr, wc, acc);
    __syncthreads();
#pragma unroll
    for (int j = 0; j < 8; ++j) {
        const int c   = tid + 256 * j;
        const int row = c >> 5, gg = c & 31;
        const int gs  = gg ^ (((row >> 2) & 3) << 2);
        const f4v vv  = *(const f4v*)&Cs[row * 128 + gs * 4];
        const int grow = m0 + row;
        if (grow >= N_NODES) continue;
        const float4 bv = *(const float4*)&biasS[gg * 4];
        const float o0 = vv[0] + bv.x, o1 = vv[1] + bv.y;
        const float o2 = vv[2] + bv.z, o3 = vv[3] + bv.w;
        if (AGG_BF16) {
            uint2* ap = (uint2*)(AggB + (size_t)grow * 64 + gg * 2);
            *ap = make_uint2(packbf(o0, o1), packbf(o2, o3));
        } else {
            *(float4*)&AggF[(size_t)grow * D + gg * 4] = make_float4(o0, o1, o2, o3);
        }
    }
}

// ---------------------------------------------------------------------------
// Layer-1 GEMM (fp32 x input, bf16 agg out) + fused edge scatter blocks
// (R0 ordering: gemm blocks first, scatter after — measured best).
// ---------------------------------------------------------------------------
__global__ __launch_bounds__(256)
void gemm1_scatter(const float* __restrict__ X, const short* __restrict__ WtL,
                   const float* __restrict__ bias,
                   short* __restrict__ Kb, unsigned int* __restrict__ QVm,
                   unsigned int* __restrict__ AggB,
                   const int* __restrict__ src, const int* __restrict__ tgt,
                   int* __restrict__ cursor, int* __restrict__ es)
{
    __shared__ __align__(16) short As[8192];    // 16 KB
    __shared__ __align__(16) short Bs[16384];   // 32 KB (doubles as Cs fp32)
    __shared__ __align__(16) float biasS[128];

    if (blockIdx.x < NBLK64) {
        gemm_tile<true, true>(blockIdx.x * 64, X, nullptr, WtL, bias,
                              Kb, QVm, nullptr, AggB, As, Bs, biasS);
    } else {
        const int e = (blockIdx.x - NBLK64) * 256 + threadIdx.x;
        if (e < N_EDGES) {
            int pos = atomicAdd(&cursor[tgt[e]], 1);
            es[pos] = src[e];
        }
    }
}

// Layer-2 GEMM (bf16 relu(h) input, fp32 agg -> d_out).
__global__ __launch_bounds__(256)
void gemm2(const short* __restrict__ Hb, const short* __restrict__ WtL,
           const float* __restrict__ bias,
           short* __restrict__ Kb, unsigned int* __restrict__ QVm,
           float* __restrict__ AggF)
{
    __shared__ __align__(16) short As[8192];
    __shared__ __align__(16) short Bs[16384];
    __shared__ __align__(16) float biasS[128];
    gemm_tile<false, false>(blockIdx.x * 64, nullptr, Hb, WtL, bias,
                            Kb, QVm, AggF, nullptr, As, Bs, biasS);
}

// ---------------------------------------------------------------------------
// Atomic-free per-node aggregation. One wave per node. 8-wide gather stage:
// per edge, lane reads ushort Q-fp8 (rec bytes 2l..2l+1) + uint V-bf16
// (rec dword 32+l) — both within one 384B line-aligned record.
// FIRST: Skip = bf16 agg1; out = bf16 relu -> Hb. Else: Skip = fp32 (d_out RMW).
// ---------------------------------------------------------------------------
template<bool FIRST>
__global__ __launch_bounds__(256)
void node_agg(const int* __restrict__ off, const int* __restrict__ es,
              const short* __restrict__ K, const unsigned int* __restrict__ QVm,
              const void* __restrict__ Skip, float* __restrict__ OutF,
              unsigned int* __restrict__ Hb)
{
    const int lane = threadIdx.x & 63;
    const int t    = __builtin_amdgcn_readfirstlane(blockIdx.x * 4 + (threadIdx.x >> 6));

    const unsigned int ku = ((const unsigned int*)K)[(size_t)t * 64 + lane];
    const float kx = bflo(ku), ky = bfhi(ku);

    float skx, sky;
    if (FIRST) {
        const unsigned int su = ((const unsigned int*)Skip)[(size_t)t * 64 + lane];
        skx = bflo(su); sky = bfhi(su);
    } else {
        const float2 s2 = ((const float2*)Skip)[(size_t)t * 64 + lane];
        skx = s2.x; sky = s2.y;
    }

    float ax = 0.f, ay = 0.f, bx = 0.f, by = 0.f;
    const int e0 = __builtin_amdgcn_readfirstlane(off[t]);
    const int e1 = __builtin_amdgcn_readfirstlane(off[t + 1]);

    int e = e0;
    for (; e + 8 <= e1; e += 8) {
        const int sv = es[e + (lane & 7)];
        unsigned int gq[8], gv[8];
#pragma unroll
        for (int u = 0; u < 8; ++u) {
            const int s = __builtin_amdgcn_readlane(sv, u);
            const unsigned int* rec = QVm + (size_t)s * QV_STRIDE;
            gq[u] = ((const unsigned short*)rec)[lane];
            gv[u] = rec[32 + lane];
        }
#pragma unroll
        for (int u = 0; u < 8; ++u) {
            const f2v qp = __builtin_amdgcn_cvt_pk_f32_fp8(gq[u], false);
            if (u & 1) {
                bx += bflo(gv[u]) * sigm(kx + qp[0]);
                by += bfhi(gv[u]) * sigm(ky + qp[1]);
            } else {
                ax += bflo(gv[u]) * sigm(kx + qp[0]);
                ay += bfhi(gv[u]) * sigm(ky + qp[1]);
            }
        }
    }
    if (e + 4 <= e1) {
        const int sv = es[e + (lane & 3)];
        unsigned int gq[4], gv[4];
#pragma unroll
        for (int u = 0; u < 4; ++u) {
            const int s = __builtin_amdgcn_readlane(sv, u);
            const unsigned int* rec = QVm + (size_t)s * QV_STRIDE;
            gq[u] = ((const unsigned short*)rec)[lane];
            gv[u] = rec[32 + lane];
        }
#pragma unroll
        for (int u = 0; u < 4; ++u) {
            const f2v qp = __builtin_amdgcn_cvt_pk_f32_fp8(gq[u], false);
            if (u & 1) {
                bx += bflo(gv[u]) * sigm(kx + qp[0]);
                by += bfhi(gv[u]) * sigm(ky + qp[1]);
            } else {
                ax += bflo(gv[u]) * sigm(kx + qp[0]);
                ay += bfhi(gv[u]) * sigm(ky + qp[1]);
            }
        }
        e += 4;
    }
    for (; e < e1; ++e) {
        const int s0 = __builtin_amdgcn_readfirstlane(es[e]);
        const unsigned int* rec = QVm + (size_t)s0 * QV_STRIDE;
        const unsigned int gq = ((const unsigned short*)rec)[lane];
        const unsigned int gv = rec[32 + lane];
        const f2v qp = __builtin_amdgcn_cvt_pk_f32_fp8(gq, false);
        ax += bflo(gv) * sigm(kx + qp[0]);
        ay += bfhi(gv) * sigm(ky + qp[1]);
    }

    const float rx = skx + ax + bx;
    const float ry = sky + ay + by;

    if (FIRST) {
        Hb[(size_t)t * 64 + lane] = packbf(fmaxf(rx, 0.f), fmaxf(ry, 0.f));
    } else {
        ((float2*)OutF)[(size_t)t * 64 + lane] = make_float2(rx, ry);
    }
}

extern "C" void kernel_launch(void* const* d_in, const int* in_sizes, int n_in,
                              void* d_out, int out_size, void* d_ws, size_t ws_size,
                              hipStream_t stream)
{
    const float* x   = (const float*)d_in[0];
    const int*   ei  = (const int*)d_in[1];
    const float* Wk1 = (const float*)d_in[2];
    const float* Wq1 = (const float*)d_in[3];
    const float* Wv1 = (const float*)d_in[4];
    const float* Ws1 = (const float*)d_in[5];
    const float* b1  = (const float*)d_in[6];
    const float* Wk2 = (const float*)d_in[7];
    const float* Wq2 = (const float*)d_in[8];
    const float* Wv2 = (const float*)d_in[9];
    const float* Ws2 = (const float*)d_in[10];
    const float* b2  = (const float*)d_in[11];

    const int* src = ei;
    const int* tgt = ei + N_EDGES;

    const size_t nd = (size_t)N_NODES * D;   // 6.4M elements
    short* kb         = (short*)d_ws;                        // bf16 K (nd shorts, 12.8MB)
    unsigned int* qvm = (unsigned int*)(kb + nd);            // merged fp8Q+bf16V records (19.2MB)
    short* hb         = (short*)(qvm + (size_t)N_NODES * QV_STRIDE);  // bf16 relu(h) (nd)
    short* ag1        = hb + nd;                             // bf16 x@Ws1+b1 (nd)
    short* wt         = ag1 + nd;                            // 8 * 16384 shorts
    int* counts    = (int*)(wt + 8 * W_FRAG_SHORTS);   // N_NODES
    int* done_ctr  = counts + N_NODES;                 // 1 (+1 pad)
    int* off       = counts + N_NODES + 2;             // N_NODES + 1
    int* cursor    = off + N_NODES + 1;                // N_NODES
    int* es        = cursor + N_NODES;                 // N_EDGES
    int* chunk_sum = es + N_EDGES;                     // NCHUNKS
    float* out = (float*)d_out;

    hipMemsetAsync(counts, 0, (N_NODES + 2) * sizeof(int), stream);
    prep_all<<<PREP_BLOCKS, 256, 0, stream>>>(Wk1, Wq1, Wv1, Ws1, Wk2, Wq2, Wv2, Ws2,
                                              wt, tgt, counts);
    csr_scan<<<NCHUNKS, 256, 0, stream>>>(counts, off, cursor, done_ctr, chunk_sum);

    // Layer 1 (+ fused edge scatter)
    gemm1_scatter<<<NBLK64 + HIST_BLOCKS, 256, 0, stream>>>(
        x, wt, b1, kb, qvm, (unsigned int*)ag1, src, tgt, cursor, es);
    node_agg<true><<<N_NODES / 4, 256, 0, stream>>>(off, es, kb, qvm,
                                                    ag1, nullptr, (unsigned int*)hb);

    // Layer 2
    gemm2<<<NBLK64, 256, 0, stream>>>(hb, wt + 4 * W_FRAG_SHORTS, b2,
                                      kb, qvm, out);
    node_agg<false><<<N_NODES / 4, 256, 0, stream>>>(off, es, kb, qvm,
                                                     out, out, nullptr);
}